// Round 8
// baseline (7931.760 us; speedup 1.0000x reference)
//
#include <hip/hip_runtime.h>
#include <hip/hip_bf16.h>

// GumbelSoftmaxTokenizer: B=8, P=16384, FEAT=6, TOK=768, MT=128, K=16, IH=256
// All inputs float32; output buffer float32 (tokens, cents, masks concat).
#define NPT   131072      // B*P
#define BATCH 8
#define PPE   16384
#define MT    128
#define KNN   16
#define TOKD  768

// ---------------------------------------------------------------------------
// L1: h1[r] = relu(features[row(r)] @ w1(6x256) + b1); row = base+r or
// gather[r] (clamped) for the KNN-recompute pass.
// ---------------------------------------------------------------------------
__global__ __launch_bounds__(256) void l1_kernel(const float* __restrict__ f,
                                                 const float* __restrict__ w1,
                                                 const float* __restrict__ b1,
                                                 float* __restrict__ h1,
                                                 int base,
                                                 const int* __restrict__ gather)
{
    const int r = blockIdx.x, n = threadIdx.x;
    int row = gather ? gather[r] : (base + r);
    row = (row < 0) ? 0 : ((row >= NPT) ? (NPT - 1) : row);
    __shared__ float fs[6];
    if (threadIdx.x < 6) fs[threadIdx.x] = f[(long)row * 6 + threadIdx.x];
    __syncthreads();
    float acc = b1[n];
#pragma unroll
    for (int k = 0; k < 6; ++k) acc += fs[k] * w1[k * 256 + n];
    h1[(long)r * 256 + n] = fmaxf(acc, 0.f);
}

// ---------------------------------------------------------------------------
// fp32 GEMM: C(MxN) = [relu]( A(MxK) @ W(KxN) + bias ). Columns K1..K-1 of A
// come from coords[:,1:5] rows (a2base+r) when K>K1 (concat for iw1).
// 128x128 block tile, BK=16, 256 threads, 8x8 micro-tile -> 16 FMA per
// ds_read_b128 (a-reads broadcast within a wave). M,N multiples of 128.
// Per-element k-accumulation order = sequential 0..K-1 (numerics unchanged).
// ---------------------------------------------------------------------------
__global__ __launch_bounds__(256) void gemm_f32(
    const float* __restrict__ A, int lda, int K, int K1,
    const float* __restrict__ A2c, int a2base,
    const float* __restrict__ W, const float* __restrict__ bias,
    float* __restrict__ C, int N, int relu)
{
    __shared__ float As[16][132];   // [k][m], row 528B (33x16B) -> b128-aligned
    __shared__ float Ws[16][128];   // [k][n]
    const int tid  = threadIdx.x;
    const int row0 = blockIdx.y << 7, col0 = blockIdx.x << 7;
    const int tx = tid & 15, ty = tid >> 4;
    float acc[8][8] = {{0.f}};
    const int ntiles = (K + 15) >> 4;
    for (int t = 0; t < ntiles; ++t) {
        const int k0 = t << 4;
        // ---- A tile: 128 rows x 16 k = 512 float4, 2 per thread
#pragma unroll
        for (int q = 0; q < 2; ++q) {
            const int l   = (tid << 1) | q;     // 0..511
            const int am  = l >> 2;             // 0..127
            const int ak4 = (l & 3) << 2;       // 0,4,8,12
            const int kg  = k0 + ak4;
            const int r   = row0 + am;
            float4 v;
            if (kg + 3 < K1) {
                v = *(const float4*)&A[(long)r * lda + kg];
            } else {
                float tmp[4];
#pragma unroll
                for (int qq = 0; qq < 4; ++qq) {
                    const int kq = kg + qq;
                    float x = 0.f;
                    if (kq < K1)     x = A[(long)r * lda + kq];
                    else if (kq < K) x = A2c[(long)(a2base + r) * 5 + 1 + (kq - K1)];
                    tmp[qq] = x;
                }
                v = make_float4(tmp[0], tmp[1], tmp[2], tmp[3]);
            }
            As[ak4 + 0][am] = v.x;
            As[ak4 + 1][am] = v.y;
            As[ak4 + 2][am] = v.z;
            As[ak4 + 3][am] = v.w;
        }
        // ---- W tile: 16 k x 128 n = 512 float4, 2 per thread (coalesced)
#pragma unroll
        for (int q = 0; q < 2; ++q) {
            const int l   = (q << 8) | tid;     // 0..511
            const int wk  = l >> 5;             // 0..15
            const int wn4 = (l & 31) << 2;      // 0..124
            const int kg  = k0 + wk;
            float4 v = make_float4(0.f, 0.f, 0.f, 0.f);
            if (kg < K) v = *(const float4*)&W[(long)kg * N + col0 + wn4];
            *(float4*)&Ws[wk][wn4] = v;
        }
        __syncthreads();
#pragma unroll
        for (int kk = 0; kk < 16; ++kk) {
            float a[8], b[8];
            *(float4*)&a[0] = *(const float4*)&As[kk][(ty << 3) + 0];
            *(float4*)&a[4] = *(const float4*)&As[kk][(ty << 3) + 4];
            *(float4*)&b[0] = *(const float4*)&Ws[kk][(tx << 3) + 0];
            *(float4*)&b[4] = *(const float4*)&Ws[kk][(tx << 3) + 4];
#pragma unroll
            for (int i = 0; i < 8; ++i)
#pragma unroll
                for (int j = 0; j < 8; ++j)
                    acc[i][j] += a[i] * b[j];
        }
        __syncthreads();
    }
#pragma unroll
    for (int i = 0; i < 8; ++i) {
        const int r = row0 + (ty << 3) + i;
#pragma unroll
        for (int jq = 0; jq < 2; ++jq) {
            const int c = col0 + (tx << 3) + (jq << 2);
            float4 v;
            v.x = acc[i][jq * 4 + 0] + bias[c + 0];
            v.y = acc[i][jq * 4 + 1] + bias[c + 1];
            v.z = acc[i][jq * 4 + 2] + bias[c + 2];
            v.w = acc[i][jq * 4 + 3] + bias[c + 3];
            if (relu) {
                v.x = fmaxf(v.x, 0.f); v.y = fmaxf(v.y, 0.f);
                v.z = fmaxf(v.z, 0.f); v.w = fmaxf(v.w, 0.f);
            }
            *(float4*)(&C[(long)r * N + c]) = v;
        }
    }
}

// ---------------------------------------------------------------------------
// LayerNorm (in place) over 256 features/row
// ---------------------------------------------------------------------------
__global__ __launch_bounds__(256) void ln_kernel(float* __restrict__ z,
                                                 const float* __restrict__ g,
                                                 const float* __restrict__ b)
{
    const int r = blockIdx.x, tid = threadIdx.x;
    float x = z[(long)r * 256 + tid];
    __shared__ float part[4];
    __shared__ float mu_s, den_s;
    float s = x;
#pragma unroll
    for (int off = 32; off; off >>= 1) s += __shfl_down(s, off);
    if ((tid & 63) == 0) part[tid >> 6] = s;
    __syncthreads();
    if (tid == 0) mu_s = (part[0] + part[1] + part[2] + part[3]) * (1.f / 256.f);
    __syncthreads();
    const float mu = mu_s;
    const float d = x - mu;
    float s2 = d * d;
#pragma unroll
    for (int off = 32; off; off >>= 1) s2 += __shfl_down(s2, off);
    if ((tid & 63) == 0) part[tid >> 6] = s2;
    __syncthreads();
    if (tid == 0)
        den_s = sqrtf((part[0] + part[1] + part[2] + part[3]) * (1.f / 256.f) + 1e-5f);
    __syncthreads();
    z[(long)r * 256 + tid] = d / den_s * g[tid] + b[tid];
}

// ---------------------------------------------------------------------------
// imp = z2 @ iw3 + ib3 ; pert = (imp + noise)/max(exp(lt),0.1)
// ---------------------------------------------------------------------------
__global__ __launch_bounds__(256) void imp_kernel(const float* __restrict__ z2,
                                                  const float* __restrict__ iw3,
                                                  const float* __restrict__ ib3,
                                                  const float* __restrict__ noise,
                                                  const float* __restrict__ lt,
                                                  float* __restrict__ pert,
                                                  int base)
{
    const int r = blockIdx.x, tid = threadIdx.x;
    float v = z2[(long)r * 256 + tid] * iw3[tid];
    __shared__ float part[4];
#pragma unroll
    for (int off = 32; off; off >>= 1) v += __shfl_down(v, off);
    if ((tid & 63) == 0) part[tid >> 6] = v;
    __syncthreads();
    if (tid == 0) {
        const float imp  = part[0] + part[1] + part[2] + part[3] + ib3[0];
        const float temp = fmaxf(expf(lt[0]), 0.1f);
        pert[base + r] = (imp + noise[base + r]) / temp;
    }
}

// ---------------------------------------------------------------------------
// top-128 per event via 4-pass radix-select on the order-preserving uint map
// (u > u' <=> f > f'), then exact tie handling (lowest indices first) and a
// 128-element bitonic sort by (value desc, index asc) = jax top_k order.
// ---------------------------------------------------------------------------
__device__ __forceinline__ unsigned fmap(float f) {
    unsigned x = __float_as_uint(f);
    return (x & 0x80000000u) ? ~x : (x | 0x80000000u);
}

__global__ __launch_bounds__(256) void topk_kernel(const float* __restrict__ pert,
                                                   const float* __restrict__ coords,
                                                   float* __restrict__ centf)
{
    const int e = blockIdx.x, tid = threadIdx.x;
    const int base = e * PPE;
    __shared__ unsigned hist[256];
    __shared__ unsigned sh_prefix;
    __shared__ int sh_need;
    unsigned prefix = 0, known = 0;
    int need = MT;
    for (int shift = 24; shift >= 0; shift -= 8) {
        hist[tid] = 0;
        __syncthreads();
        for (int i = tid; i < PPE; i += 256) {
            const unsigned u = fmap(pert[base + i]);
            if ((u & known) == prefix) atomicAdd(&hist[(u >> shift) & 255u], 1u);
        }
        __syncthreads();
        if (tid == 0) {
            int cum = 0, b = 255;
            for (; b > 0; --b) { cum += (int)hist[b]; if (cum >= need) break; }
            if (cum < need) { cum += (int)hist[0]; b = 0; }   // b==0 catch-all
            sh_need   = need - (cum - (int)hist[b]);
            sh_prefix = prefix | ((unsigned)b << shift);
        }
        __syncthreads();
        need   = sh_need;
        prefix = sh_prefix;
        known |= (255u << shift);
        __syncthreads();
    }
    const unsigned T = prefix;     // exact threshold
    const int need_eq = need;      // how many ==T to take (lowest index first)

    __shared__ unsigned selu[MT];
    __shared__ int      seli[MT];
    __shared__ int cgt, ceq;
    __shared__ int eqbuf[256];
    if (tid == 0) { cgt = 0; ceq = 0; }
    __syncthreads();
    for (int i = tid; i < PPE; i += 256) {
        const unsigned u = fmap(pert[base + i]);
        if (u > T)       { int p = atomicAdd(&cgt, 1); selu[p] = u; seli[p] = i; }
        else if (u == T) { int p = atomicAdd(&ceq, 1); if (p < 256) eqbuf[p] = i; }
    }
    __syncthreads();
    const int ngt = cgt;           // == MT - need_eq by construction
    if (ceq <= 256) {
        if (tid >= ceq) eqbuf[tid] = 0x7FFFFFFF;
        __syncthreads();
        for (int k = 2; k <= 256; k <<= 1)
            for (int j = k >> 1; j > 0; j >>= 1) {
                const int l = tid ^ j;
                if (l > tid) {
                    const int a = eqbuf[tid], b = eqbuf[l];
                    const bool up = ((tid & k) == 0);
                    if (up ? (a > b) : (a < b)) { eqbuf[tid] = b; eqbuf[l] = a; }
                }
                __syncthreads();
            }
        if (tid < need_eq) { selu[ngt + tid] = T; seli[ngt + tid] = eqbuf[tid]; }
    } else if (tid == 0) {
        int cur = -1;
        for (int q = 0; q < need_eq; ++q) {
            int best = 0x7FFFFFFF;
            for (int i = 0; i < PPE; ++i)
                if (i > cur && fmap(pert[base + i]) == T && i < best) best = i;
            selu[ngt + q] = T; seli[ngt + q] = best; cur = best;
        }
    }
    __syncthreads();
    __shared__ unsigned long long key[MT];
    if (tid < MT)
        key[tid] = ((unsigned long long)selu[tid] << 32) | (unsigned)(~seli[tid]);
    __syncthreads();
    for (int k = 2; k <= MT; k <<= 1)
        for (int j = k >> 1; j > 0; j >>= 1) {
            if (tid < MT) {
                const int l = tid ^ j;
                if (l > tid) {
                    const unsigned long long a = key[tid], b = key[l];
                    const bool up = ((tid & k) == 0);
                    if (up ? (a < b) : (a > b)) { key[tid] = b; key[l] = a; }
                }
            }
            __syncthreads();
        }
    if (tid < MT) {
        const int idx = (int)(~(unsigned)(key[tid] & 0xFFFFFFFFu));
        const long cb = (long)(base + idx) * 5;
        centf[(long)(e * MT + tid) * 4 + 0] = coords[cb + 1];
        centf[(long)(e * MT + tid) * 4 + 1] = coords[cb + 2];
        centf[(long)(e * MT + tid) * 4 + 2] = coords[cb + 3];
        centf[(long)(e * MT + tid) * 4 + 3] = coords[cb + 4];
    }
}

// ---------------------------------------------------------------------------
// per (event,centroid): 16-NN over 16384 points (smallest d2, ties -> lower
// index = jax top_k(-d2)). Sequential 4-term fp32 sum matches the np ref.
// ---------------------------------------------------------------------------
__global__ __launch_bounds__(256) void knn_kernel(const float* __restrict__ coords,
                                                  const float* __restrict__ centf,
                                                  int* __restrict__ knn_idx)
{
    const int blk = blockIdx.x;           // e*128 + m
    const int e = blk >> 7;
    const int tid = threadIdx.x;
    const int base = e * PPE;
    const float c0 = centf[(long)blk * 4 + 0];
    const float c1 = centf[(long)blk * 4 + 1];
    const float c2 = centf[(long)blk * 4 + 2];
    const float c3 = centf[(long)blk * 4 + 3];
    float ld[KNN]; int li[KNN];
#pragma unroll
    for (int i = 0; i < KNN; ++i) { ld[i] = 3.4e38f; li[i] = 0x7FFFFFFF; }
    for (int p = tid; p < PPE; p += 256) {
        const long cb = (long)(base + p) * 5;
        const float x0 = coords[cb + 1];
        const float x1 = coords[cb + 2];
        const float x2 = coords[cb + 3];
        const float x3 = coords[cb + 4];
        const float q0 = __fmul_rn(c0 - x0, c0 - x0);
        const float q1 = __fmul_rn(c1 - x1, c1 - x1);
        const float q2 = __fmul_rn(c2 - x2, c2 - x2);
        const float q3 = __fmul_rn(c3 - x3, c3 - x3);
        const float d  = __fadd_rn(__fadd_rn(__fadd_rn(q0, q1), q2), q3);
        if (d < ld[KNN - 1] || (d == ld[KNN - 1] && p < li[KNN - 1])) {
            int j = KNN - 1;
            while (j > 0 && (d < ld[j - 1] || (d == ld[j - 1] && p < li[j - 1]))) {
                ld[j] = ld[j - 1]; li[j] = li[j - 1]; --j;
            }
            ld[j] = d; li[j] = p;
        }
    }
    __shared__ float hv[256];
    __shared__ int   hi[256];
    __shared__ int   ho[256];
    int ptr = 0;
    for (int r = 0; r < KNN; ++r) {
        hv[tid] = (ptr < KNN) ? ld[ptr] : 3.4e38f;
        hi[tid] = (ptr < KNN) ? li[ptr] : 0x7FFFFFFF;
        ho[tid] = tid;
        __syncthreads();
        for (int s = 128; s > 0; s >>= 1) {
            if (tid < s) {
                const float v2 = hv[tid + s]; const int i2 = hi[tid + s];
                if (v2 < hv[tid] || (v2 == hv[tid] && i2 < hi[tid])) {
                    hv[tid] = v2; hi[tid] = i2; ho[tid] = ho[tid + s];
                }
            }
            __syncthreads();
        }
        if (tid == ho[0]) ptr++;
        if (tid == 0) {
            int ix = hi[0];
            ix = (ix < 0) ? 0 : ((ix >= PPE) ? (PPE - 1) : ix);
            knn_idx[blk * KNN + r] = base + ix;
        }
        __syncthreads();
    }
}

// ---------------------------------------------------------------------------
// pooled[blk][t] = max over 16 recomputed-pf neighbor rows (chunk layout)
// ---------------------------------------------------------------------------
__global__ __launch_bounds__(256) void pool_kernel(const float* __restrict__ pf_nbr,
                                                   float* __restrict__ pooled)
{
    const int blk = blockIdx.x, tid = threadIdx.x;
    for (int t = tid; t < TOKD; t += 256) {
        float mx = -3.4e38f;
#pragma unroll
        for (int j = 0; j < KNN; ++j)
            mx = fmaxf(mx, pf_nbr[(long)(blk * KNN + j) * TOKD + t]);
        pooled[(long)blk * TOKD + t] = mx;
    }
}

// ---------------------------------------------------------------------------
// per event: stable rank by cent[:,3] asc + emit tokens/cents/masks as FP32.
// ---------------------------------------------------------------------------
__global__ __launch_bounds__(256) void emit_kernel(const float* __restrict__ centf,
                                                   const float* __restrict__ tokf_e,
                                                   int e, float* __restrict__ out,
                                                   long out_size)
{
    const int tid = threadIdx.x;
    __shared__ float tv[MT];
    __shared__ int   rk[MT];
    if (tid < MT) tv[tid] = centf[(long)(e * MT + tid) * 4 + 3];
    __syncthreads();
    if (tid < MT) {
        const float t = tv[tid]; int r = 0;
        for (int j = 0; j < MT; ++j)
            r += (tv[j] < t || (tv[j] == t && j < tid)) ? 1 : 0;
        rk[tid] = r;
    }
    __syncthreads();
    const long cent_off = (long)BATCH * MT * TOKD;         // 786432
    const long mask_off = cent_off + (long)BATCH * MT * 4; // 790528
    for (int idx = tid; idx < MT * TOKD; idx += 256) {
        const int i = idx / TOKD, t = idx % TOKD;
        const long g = ((long)e * MT + rk[i]) * TOKD + t;
        if (g < out_size) out[g] = tokf_e[(long)i * TOKD + t];
    }
    for (int idx = tid; idx < MT * 4; idx += 256) {
        const int i = idx >> 2, d = idx & 3;
        const long g = cent_off + ((long)e * MT + rk[i]) * 4 + d;
        if (g < out_size) out[g] = centf[((long)e * MT + i) * 4 + d];
    }
    for (int idx = tid; idx < MT; idx += 256) {
        const long g = mask_off + (long)e * MT + idx;
        if (g < out_size) out[g] = 1.0f;
    }
}

// ---------------------------------------------------------------------------
extern "C" void kernel_launch(void* const* d_in, const int* in_sizes, int n_in,
                              void* d_out, int out_size, void* d_ws, size_t ws_size,
                              hipStream_t stream)
{
    const float* coords = (const float*)d_in[0];
    const float* feats  = (const float*)d_in[1];
    const float* lt     = (const float*)d_in[2];
    const float* w1  = (const float*)d_in[3];  const float* b1  = (const float*)d_in[4];
    const float* w2  = (const float*)d_in[5];  const float* b2  = (const float*)d_in[6];
    const float* w3  = (const float*)d_in[7];  const float* b3  = (const float*)d_in[8];
    const float* w4  = (const float*)d_in[9];  const float* b4  = (const float*)d_in[10];
    const float* iw1 = (const float*)d_in[11]; const float* ib1 = (const float*)d_in[12];
    const float* lng = (const float*)d_in[13]; const float* lnb = (const float*)d_in[14];
    const float* iw2 = (const float*)d_in[15]; const float* ib2 = (const float*)d_in[16];
    const float* iw3 = (const float*)d_in[17]; const float* ib3 = (const float*)d_in[18];
    const float* nw1 = (const float*)d_in[19]; const float* nb1 = (const float*)d_in[20];
    const float* nw2 = (const float*)d_in[21]; const float* nb2 = (const float*)d_in[22];
    const float* noise = (const float*)d_in[23];

    // fixed ws (floats): pert + centf + knn + pooled = 937,984 (~3.75 MB)
    // ping-pong region: 2 x ch x 768 floats (activation chain max width 768)
    const size_t FIXED  = (size_t)NPT + 4096 + 16384 + (size_t)1024 * TOKD;
    const size_t perrow = 1536;
    int ch = 128;
    while (ch < PPE && (FIXED + (size_t)(ch * 2) * perrow) * 4 <= ws_size) ch <<= 1;

    float* pert   = (float*)d_ws;                       // NPT
    float* centf  = pert + NPT;                         // 1024*4
    int*   knn    = (int*)(centf + 4096);               // 16384 ints
    float* pooled = (float*)(knn + 16384);              // 1024*768
    float* bufA   = pooled + (size_t)1024 * TOKD;       // ch*768
    float* bufB   = bufA + (size_t)ch * 768;            // ch*768

    // ---- chunked MLP: features -> pert (selection chain, fp32) ----
    for (int ck = 0; ck < NPT / ch; ++ck) {
        const int base = ck * ch;
        l1_kernel<<<dim3(ch), dim3(256), 0, stream>>>(feats, w1, b1, bufA, base, nullptr);
        gemm_f32<<<dim3(512 / 128, ch / 128), dim3(256), 0, stream>>>(
            bufA, 256, 256, 256, nullptr, 0, w2, b2, bufB, 512, 1);
        gemm_f32<<<dim3(768 / 128, ch / 128), dim3(256), 0, stream>>>(
            bufB, 512, 512, 512, nullptr, 0, w3, b3, bufA, 768, 1);
        gemm_f32<<<dim3(768 / 128, ch / 128), dim3(256), 0, stream>>>(
            bufA, 768, 768, 768, nullptr, 0, w4, b4, bufB, 768, 0);
        gemm_f32<<<dim3(256 / 128, ch / 128), dim3(256), 0, stream>>>(
            bufB, 768, 772, 768, coords, base, iw1, ib1, bufA, 256, 1);
        ln_kernel<<<dim3(ch), dim3(256), 0, stream>>>(bufA, lng, lnb);
        gemm_f32<<<dim3(256 / 128, ch / 128), dim3(256), 0, stream>>>(
            bufA, 256, 256, 256, nullptr, 0, iw2, ib2, bufB, 256, 1);
        imp_kernel<<<dim3(ch), dim3(256), 0, stream>>>(bufB, iw3, ib3, noise, lt, pert, base);
    }

    // ---- selection + KNN ----
    topk_kernel<<<dim3(BATCH), dim3(256), 0, stream>>>(pert, coords, centf);
    knn_kernel<<<dim3(BATCH * MT), dim3(256), 0, stream>>>(coords, centf, knn);

    // ---- recompute pf for the 16384 gathered neighbor rows (chunked), pool ----
    const int NBR = BATCH * MT * KNN;   // 16384
    for (int rc = 0; rc < NBR / ch; ++rc) {
        l1_kernel<<<dim3(ch), dim3(256), 0, stream>>>(feats, w1, b1, bufA, 0, knn + (size_t)rc * ch);
        gemm_f32<<<dim3(512 / 128, ch / 128), dim3(256), 0, stream>>>(
            bufA, 256, 256, 256, nullptr, 0, w2, b2, bufB, 512, 1);
        gemm_f32<<<dim3(768 / 128, ch / 128), dim3(256), 0, stream>>>(
            bufB, 512, 512, 512, nullptr, 0, w3, b3, bufA, 768, 1);
        gemm_f32<<<dim3(768 / 128, ch / 128), dim3(256), 0, stream>>>(
            bufA, 768, 768, 768, nullptr, 0, w4, b4, bufB, 768, 0);
        pool_kernel<<<dim3(ch / KNN), dim3(256), 0, stream>>>(
            bufB, pooled + (size_t)rc * (ch / KNN) * TOKD);
    }

    // ---- token MLP (1024x768) + emit ----
    if (ch >= 1024) {
        float* t1 = bufA, *tokf = bufB;
        gemm_f32<<<dim3(768 / 128, 1024 / 128), dim3(256), 0, stream>>>(
            pooled, 768, 768, 768, nullptr, 0, nw1, nb1, t1, 768, 1);
        gemm_f32<<<dim3(768 / 128, 1024 / 128), dim3(256), 0, stream>>>(
            t1, 768, 768, 768, nullptr, 0, nw2, nb2, tokf, 768, 0);
        for (int e = 0; e < BATCH; ++e)
            emit_kernel<<<dim3(1), dim3(256), 0, stream>>>(
                centf, tokf + (size_t)e * MT * TOKD, e, (float*)d_out, (long)out_size);
    } else {
        for (int e = 0; e < BATCH; ++e) {
            gemm_f32<<<dim3(768 / 128, 1), dim3(256), 0, stream>>>(
                pooled + (size_t)e * MT * TOKD, 768, 768, 768, nullptr, 0,
                nw1, nb1, bufA, 768, 1);
            gemm_f32<<<dim3(768 / 128, 1), dim3(256), 0, stream>>>(
                bufA, 768, 768, 768, nullptr, 0, nw2, nb2, bufB, 768, 0);
            emit_kernel<<<dim3(1), dim3(256), 0, stream>>>(
                centf, bufB, e, (float*)d_out, (long)out_size);
        }
    }
}

// Round 9
// 4481.258 us; speedup vs baseline: 1.7700x; 1.7700x over previous
//
#include <hip/hip_runtime.h>
#include <hip/hip_bf16.h>

// GumbelSoftmaxTokenizer: B=8, P=16384, FEAT=6, TOK=768, MT=128, K=16, IH=256
// All inputs float32; output buffer float32 (tokens, cents, masks concat).
#define NPT   131072      // B*P
#define BATCH 8
#define PPE   16384
#define MT    128
#define KNN   16
#define TOKD  768

typedef short bf16x8 __attribute__((ext_vector_type(8)));
typedef float f32x4  __attribute__((ext_vector_type(4)));

#define LDK 56   // row stride (in bf16) of LDS fragment arrays; 112B rows

__device__ __forceinline__ unsigned pack_hi(unsigned u0, unsigned u1) {
    return (u0 >> 16) | (u1 & 0xFFFF0000u);   // bf16 pair (e0,e1), truncated
}

// ---------------------------------------------------------------------------
// L1: h1[r] = relu(features[row(r)] @ w1(6x256) + b1); row = base+r or
// gather[r] (clamped) for the KNN-recompute pass.
// ---------------------------------------------------------------------------
__global__ __launch_bounds__(256) void l1_kernel(const float* __restrict__ f,
                                                 const float* __restrict__ w1,
                                                 const float* __restrict__ b1,
                                                 float* __restrict__ h1,
                                                 int base,
                                                 const int* __restrict__ gather)
{
    const int r = blockIdx.x, n = threadIdx.x;
    int row = gather ? gather[r] : (base + r);
    row = (row < 0) ? 0 : ((row >= NPT) ? (NPT - 1) : row);
    __shared__ float fs[6];
    if (threadIdx.x < 6) fs[threadIdx.x] = f[(long)row * 6 + threadIdx.x];
    __syncthreads();
    float acc = b1[n];
#pragma unroll
    for (int k = 0; k < 6; ++k) acc += fs[k] * w1[k * 256 + n];
    h1[(long)r * 256 + n] = fmaxf(acc, 0.f);
}

// ---------------------------------------------------------------------------
// Split-bf16 MFMA GEMM: C(MxN) = [relu](A(MxK,f32) @ W(KxN,f32) + bias).
// Each f32 = hi(bf16,trunc) + lo(bf16,trunc of residual); 4 MFMA products
// (hh,hl,lh,ll) accumulated in fp32 => ~8e-6 relative accuracy.
// Block 128x128, BK=32, 256 thr = 4 waves; wave computes 32 rows x 128 cols
// as 2x8 16x16 C-tiles (64 mfma_f32_16x16x32_bf16 per wave per k-step).
// A cols K1..K-1 come from coords[:,1:5] rows (a2base+r) when A2c != null.
// M,N multiples of 128; K arbitrary (guarded).
// Fragment layouts (HW-verified, guide §3): A[m=lane&15][k=quad*8+j],
// B[k=quad*8+j][n=lane&15], C/D col=lane&15 row=quad*4+reg.
// ---------------------------------------------------------------------------
__global__ __launch_bounds__(256) void gemm_mf(
    const float* __restrict__ A, int lda, int K, int K1,
    const float* __restrict__ A2c, int a2base,
    const float* __restrict__ W, const float* __restrict__ bias,
    float* __restrict__ C, int N, int relu)
{
    __shared__ short Ah[128 * LDK];
    __shared__ short Al[128 * LDK];
    __shared__ short Bh[128 * LDK];
    __shared__ short Bl[128 * LDK];
    const int tid  = threadIdx.x;
    const int row0 = blockIdx.y << 7, col0 = blockIdx.x << 7;
    const int wave = tid >> 6, lane = tid & 63;
    const int q = lane >> 4, l16 = lane & 15;

    f32x4 acc[2][8];
#pragma unroll
    for (int mt = 0; mt < 2; ++mt)
#pragma unroll
        for (int nt = 0; nt < 8; ++nt)
            acc[mt][nt] = (f32x4){0.f, 0.f, 0.f, 0.f};

    // B staging coords: thread covers col n, k-half kh (16 k values)
    const int bn = tid & 127, bkh = (tid >> 7) << 4;

    const int nk = (K + 31) >> 5;
    for (int t = 0; t < nk; ++t) {
        const int k0 = t << 5;
        // ---- stage A: 128 rows x 32 k (f32 -> hi/lo bf16), 4 float4/thread
#pragma unroll
        for (int s = 0; s < 4; ++s) {
            const int l  = (s << 8) + tid;      // 0..1023
            const int m  = l >> 3;
            const int k4 = (l & 7) << 2;
            const int kg = k0 + k4;
            const int r  = row0 + m;
            float4 v;
            if (kg + 3 < K1) {
                v = *(const float4*)&A[(long)r * lda + kg];
            } else {
                float tmp[4];
#pragma unroll
                for (int qq = 0; qq < 4; ++qq) {
                    const int kq = kg + qq;
                    float x = 0.f;
                    if (kq < K1)      x = A[(long)r * lda + kq];
                    else if (kq < K)  x = A2c[(long)(a2base + r) * 5 + 1 + (kq - K1)];
                    tmp[qq] = x;
                }
                v = make_float4(tmp[0], tmp[1], tmp[2], tmp[3]);
            }
            const unsigned u0 = __float_as_uint(v.x), u1 = __float_as_uint(v.y);
            const unsigned u2 = __float_as_uint(v.z), u3 = __float_as_uint(v.w);
            const unsigned r0 = __float_as_uint(v.x - __uint_as_float(u0 & 0xFFFF0000u));
            const unsigned r1 = __float_as_uint(v.y - __uint_as_float(u1 & 0xFFFF0000u));
            const unsigned r2 = __float_as_uint(v.z - __uint_as_float(u2 & 0xFFFF0000u));
            const unsigned r3 = __float_as_uint(v.w - __uint_as_float(u3 & 0xFFFF0000u));
            *(int2*)&Ah[m * LDK + k4] = make_int2((int)pack_hi(u0, u1), (int)pack_hi(u2, u3));
            *(int2*)&Al[m * LDK + k4] = make_int2((int)pack_hi(r0, r1), (int)pack_hi(r2, r3));
        }
        // ---- stage W: 32 k x 128 n -> Bh/Bl[n][k]; 16 dword loads/thread
        {
            unsigned h[8], lo[8];
#pragma unroll
            for (int p = 0; p < 8; ++p) {
                const int j0 = p << 1;
                float x0 = 0.f, x1 = 0.f;
                if (k0 + bkh + j0 < K)     x0 = W[(long)(k0 + bkh + j0) * N + col0 + bn];
                if (k0 + bkh + j0 + 1 < K) x1 = W[(long)(k0 + bkh + j0 + 1) * N + col0 + bn];
                const unsigned u0 = __float_as_uint(x0), u1 = __float_as_uint(x1);
                const unsigned r0 = __float_as_uint(x0 - __uint_as_float(u0 & 0xFFFF0000u));
                const unsigned r1 = __float_as_uint(x1 - __uint_as_float(u1 & 0xFFFF0000u));
                h[p]  = pack_hi(u0, u1);
                lo[p] = pack_hi(r0, r1);
            }
            *(int4*)&Bh[bn * LDK + bkh + 0] = make_int4((int)h[0], (int)h[1], (int)h[2], (int)h[3]);
            *(int4*)&Bh[bn * LDK + bkh + 8] = make_int4((int)h[4], (int)h[5], (int)h[6], (int)h[7]);
            *(int4*)&Bl[bn * LDK + bkh + 0] = make_int4((int)lo[0], (int)lo[1], (int)lo[2], (int)lo[3]);
            *(int4*)&Bl[bn * LDK + bkh + 8] = make_int4((int)lo[4], (int)lo[5], (int)lo[6], (int)lo[7]);
        }
        __syncthreads();
        // ---- MFMA: wave rows [wave*32, +32), 2 m-tiles x 8 n-tiles
        bf16x8 ah[2], al[2];
#pragma unroll
        for (int mt = 0; mt < 2; ++mt) {
            const int mrow = (wave << 5) + (mt << 4) + l16;
            ah[mt] = *(const bf16x8*)&Ah[mrow * LDK + (q << 3)];
            al[mt] = *(const bf16x8*)&Al[mrow * LDK + (q << 3)];
        }
#pragma unroll
        for (int nt = 0; nt < 8; ++nt) {
            const int ncol = (nt << 4) + l16;
            const bf16x8 bh = *(const bf16x8*)&Bh[ncol * LDK + (q << 3)];
            const bf16x8 bl = *(const bf16x8*)&Bl[ncol * LDK + (q << 3)];
#pragma unroll
            for (int mt = 0; mt < 2; ++mt) {
                acc[mt][nt] = __builtin_amdgcn_mfma_f32_16x16x32_bf16(ah[mt], bh, acc[mt][nt], 0, 0, 0);
                acc[mt][nt] = __builtin_amdgcn_mfma_f32_16x16x32_bf16(ah[mt], bl, acc[mt][nt], 0, 0, 0);
                acc[mt][nt] = __builtin_amdgcn_mfma_f32_16x16x32_bf16(al[mt], bh, acc[mt][nt], 0, 0, 0);
                acc[mt][nt] = __builtin_amdgcn_mfma_f32_16x16x32_bf16(al[mt], bl, acc[mt][nt], 0, 0, 0);
            }
        }
        __syncthreads();
    }
    // ---- epilogue: C/D layout col=lane&15, row=quad*4+reg
#pragma unroll
    for (int mt = 0; mt < 2; ++mt)
#pragma unroll
        for (int nt = 0; nt < 8; ++nt) {
            const int col = col0 + (nt << 4) + l16;
            const float bs = bias[col];
#pragma unroll
            for (int rg = 0; rg < 4; ++rg) {
                const int row = row0 + (wave << 5) + (mt << 4) + (q << 2) + rg;
                float v = acc[mt][nt][rg] + bs;
                if (relu) v = fmaxf(v, 0.f);
                C[(long)row * N + col] = v;
            }
        }
}

// ---------------------------------------------------------------------------
// LayerNorm (in place) over 256 features/row
// ---------------------------------------------------------------------------
__global__ __launch_bounds__(256) void ln_kernel(float* __restrict__ z,
                                                 const float* __restrict__ g,
                                                 const float* __restrict__ b)
{
    const int r = blockIdx.x, tid = threadIdx.x;
    float x = z[(long)r * 256 + tid];
    __shared__ float part[4];
    __shared__ float mu_s, den_s;
    float s = x;
#pragma unroll
    for (int off = 32; off; off >>= 1) s += __shfl_down(s, off);
    if ((tid & 63) == 0) part[tid >> 6] = s;
    __syncthreads();
    if (tid == 0) mu_s = (part[0] + part[1] + part[2] + part[3]) * (1.f / 256.f);
    __syncthreads();
    const float mu = mu_s;
    const float d = x - mu;
    float s2 = d * d;
#pragma unroll
    for (int off = 32; off; off >>= 1) s2 += __shfl_down(s2, off);
    if ((tid & 63) == 0) part[tid >> 6] = s2;
    __syncthreads();
    if (tid == 0)
        den_s = sqrtf((part[0] + part[1] + part[2] + part[3]) * (1.f / 256.f) + 1e-5f);
    __syncthreads();
    z[(long)r * 256 + tid] = d / den_s * g[tid] + b[tid];
}

// ---------------------------------------------------------------------------
// imp = z2 @ iw3 + ib3 ; pert = (imp + noise)/max(exp(lt),0.1)
// ---------------------------------------------------------------------------
__global__ __launch_bounds__(256) void imp_kernel(const float* __restrict__ z2,
                                                  const float* __restrict__ iw3,
                                                  const float* __restrict__ ib3,
                                                  const float* __restrict__ noise,
                                                  const float* __restrict__ lt,
                                                  float* __restrict__ pert,
                                                  int base)
{
    const int r = blockIdx.x, tid = threadIdx.x;
    float v = z2[(long)r * 256 + tid] * iw3[tid];
    __shared__ float part[4];
#pragma unroll
    for (int off = 32; off; off >>= 1) v += __shfl_down(v, off);
    if ((tid & 63) == 0) part[tid >> 6] = v;
    __syncthreads();
    if (tid == 0) {
        const float imp  = part[0] + part[1] + part[2] + part[3] + ib3[0];
        const float temp = fmaxf(expf(lt[0]), 0.1f);
        pert[base + r] = (imp + noise[base + r]) / temp;
    }
}

// ---------------------------------------------------------------------------
// top-128 per event via 4-pass radix-select (order-preserving uint map),
// exact tie handling (lowest indices first), 128-elem bitonic sort by
// (value desc, index asc) = jax top_k order.
// ---------------------------------------------------------------------------
__device__ __forceinline__ unsigned fmap(float f) {
    unsigned x = __float_as_uint(f);
    return (x & 0x80000000u) ? ~x : (x | 0x80000000u);
}

__global__ __launch_bounds__(256) void topk_kernel(const float* __restrict__ pert,
                                                   const float* __restrict__ coords,
                                                   float* __restrict__ centf)
{
    const int e = blockIdx.x, tid = threadIdx.x;
    const int base = e * PPE;
    __shared__ unsigned hist[256];
    __shared__ unsigned sh_prefix;
    __shared__ int sh_need;
    unsigned prefix = 0, known = 0;
    int need = MT;
    for (int shift = 24; shift >= 0; shift -= 8) {
        hist[tid] = 0;
        __syncthreads();
        for (int i = tid; i < PPE; i += 256) {
            const unsigned u = fmap(pert[base + i]);
            if ((u & known) == prefix) atomicAdd(&hist[(u >> shift) & 255u], 1u);
        }
        __syncthreads();
        if (tid == 0) {
            int cum = 0, b = 255;
            for (; b > 0; --b) { cum += (int)hist[b]; if (cum >= need) break; }
            if (cum < need) { cum += (int)hist[0]; b = 0; }
            sh_need   = need - (cum - (int)hist[b]);
            sh_prefix = prefix | ((unsigned)b << shift);
        }
        __syncthreads();
        need   = sh_need;
        prefix = sh_prefix;
        known |= (255u << shift);
        __syncthreads();
    }
    const unsigned T = prefix;
    const int need_eq = need;

    __shared__ unsigned selu[MT];
    __shared__ int      seli[MT];
    __shared__ int cgt, ceq;
    __shared__ int eqbuf[256];
    if (tid == 0) { cgt = 0; ceq = 0; }
    __syncthreads();
    for (int i = tid; i < PPE; i += 256) {
        const unsigned u = fmap(pert[base + i]);
        if (u > T)       { int p = atomicAdd(&cgt, 1); selu[p] = u; seli[p] = i; }
        else if (u == T) { int p = atomicAdd(&ceq, 1); if (p < 256) eqbuf[p] = i; }
    }
    __syncthreads();
    const int ngt = cgt;
    if (ceq <= 256) {
        if (tid >= ceq) eqbuf[tid] = 0x7FFFFFFF;
        __syncthreads();
        for (int k = 2; k <= 256; k <<= 1)
            for (int j = k >> 1; j > 0; j >>= 1) {
                const int l = tid ^ j;
                if (l > tid) {
                    const int a = eqbuf[tid], b = eqbuf[l];
                    const bool up = ((tid & k) == 0);
                    if (up ? (a > b) : (a < b)) { eqbuf[tid] = b; eqbuf[l] = a; }
                }
                __syncthreads();
            }
        if (tid < need_eq) { selu[ngt + tid] = T; seli[ngt + tid] = eqbuf[tid]; }
    } else if (tid == 0) {
        int cur = -1;
        for (int qq = 0; qq < need_eq; ++qq) {
            int best = 0x7FFFFFFF;
            for (int i = 0; i < PPE; ++i)
                if (i > cur && fmap(pert[base + i]) == T && i < best) best = i;
            selu[ngt + qq] = T; seli[ngt + qq] = best; cur = best;
        }
    }
    __syncthreads();
    __shared__ unsigned long long key[MT];
    if (tid < MT)
        key[tid] = ((unsigned long long)selu[tid] << 32) | (unsigned)(~seli[tid]);
    __syncthreads();
    for (int k = 2; k <= MT; k <<= 1)
        for (int j = k >> 1; j > 0; j >>= 1) {
            if (tid < MT) {
                const int l = tid ^ j;
                if (l > tid) {
                    const unsigned long long a = key[tid], b = key[l];
                    const bool up = ((tid & k) == 0);
                    if (up ? (a < b) : (a > b)) { key[tid] = b; key[l] = a; }
                }
            }
            __syncthreads();
        }
    if (tid < MT) {
        const int idx = (int)(~(unsigned)(key[tid] & 0xFFFFFFFFu));
        const long cb = (long)(base + idx) * 5;
        centf[(long)(e * MT + tid) * 4 + 0] = coords[cb + 1];
        centf[(long)(e * MT + tid) * 4 + 1] = coords[cb + 2];
        centf[(long)(e * MT + tid) * 4 + 2] = coords[cb + 3];
        centf[(long)(e * MT + tid) * 4 + 3] = coords[cb + 4];
    }
}

// ---------------------------------------------------------------------------
// per (event,centroid): 16-NN over 16384 points (smallest d2, ties -> lower
// index = jax top_k(-d2)). Sequential 4-term fp32 sum matches the np ref.
// ---------------------------------------------------------------------------
__global__ __launch_bounds__(256) void knn_kernel(const float* __restrict__ coords,
                                                  const float* __restrict__ centf,
                                                  int* __restrict__ knn_idx)
{
    const int blk = blockIdx.x;
    const int e = blk >> 7;
    const int tid = threadIdx.x;
    const int base = e * PPE;
    const float c0 = centf[(long)blk * 4 + 0];
    const float c1 = centf[(long)blk * 4 + 1];
    const float c2 = centf[(long)blk * 4 + 2];
    const float c3 = centf[(long)blk * 4 + 3];
    float ld[KNN]; int li[KNN];
#pragma unroll
    for (int i = 0; i < KNN; ++i) { ld[i] = 3.4e38f; li[i] = 0x7FFFFFFF; }
    for (int p = tid; p < PPE; p += 256) {
        const long cb = (long)(base + p) * 5;
        const float x0 = coords[cb + 1];
        const float x1 = coords[cb + 2];
        const float x2 = coords[cb + 3];
        const float x3 = coords[cb + 4];
        const float q0 = __fmul_rn(c0 - x0, c0 - x0);
        const float q1 = __fmul_rn(c1 - x1, c1 - x1);
        const float q2 = __fmul_rn(c2 - x2, c2 - x2);
        const float q3 = __fmul_rn(c3 - x3, c3 - x3);
        const float d  = __fadd_rn(__fadd_rn(__fadd_rn(q0, q1), q2), q3);
        if (d < ld[KNN - 1] || (d == ld[KNN - 1] && p < li[KNN - 1])) {
            int j = KNN - 1;
            while (j > 0 && (d < ld[j - 1] || (d == ld[j - 1] && p < li[j - 1]))) {
                ld[j] = ld[j - 1]; li[j] = li[j - 1]; --j;
            }
            ld[j] = d; li[j] = p;
        }
    }
    __shared__ float hv[256];
    __shared__ int   hi2[256];
    __shared__ int   ho[256];
    int ptr = 0;
    for (int r = 0; r < KNN; ++r) {
        hv[tid]  = (ptr < KNN) ? ld[ptr] : 3.4e38f;
        hi2[tid] = (ptr < KNN) ? li[ptr] : 0x7FFFFFFF;
        ho[tid]  = tid;
        __syncthreads();
        for (int s = 128; s > 0; s >>= 1) {
            if (tid < s) {
                const float v2 = hv[tid + s]; const int i2 = hi2[tid + s];
                if (v2 < hv[tid] || (v2 == hv[tid] && i2 < hi2[tid])) {
                    hv[tid] = v2; hi2[tid] = i2; ho[tid] = ho[tid + s];
                }
            }
            __syncthreads();
        }
        if (tid == ho[0]) ptr++;
        if (tid == 0) {
            int ix = hi2[0];
            ix = (ix < 0) ? 0 : ((ix >= PPE) ? (PPE - 1) : ix);
            knn_idx[blk * KNN + r] = base + ix;
        }
        __syncthreads();
    }
}

// ---------------------------------------------------------------------------
// pooled[blk][t] = max over 16 recomputed-pf neighbor rows (chunk layout)
// ---------------------------------------------------------------------------
__global__ __launch_bounds__(256) void pool_kernel(const float* __restrict__ pf_nbr,
                                                   float* __restrict__ pooled)
{
    const int blk = blockIdx.x, tid = threadIdx.x;
    for (int t = tid; t < TOKD; t += 256) {
        float mx = -3.4e38f;
#pragma unroll
        for (int j = 0; j < KNN; ++j)
            mx = fmaxf(mx, pf_nbr[(long)(blk * KNN + j) * TOKD + t]);
        pooled[(long)blk * TOKD + t] = mx;
    }
}

// ---------------------------------------------------------------------------
// per event: stable rank by cent[:,3] asc + emit tokens/cents/masks as FP32.
// ---------------------------------------------------------------------------
__global__ __launch_bounds__(256) void emit_kernel(const float* __restrict__ centf,
                                                   const float* __restrict__ tokf_e,
                                                   int e, float* __restrict__ out,
                                                   long out_size)
{
    const int tid = threadIdx.x;
    __shared__ float tv[MT];
    __shared__ int   rk[MT];
    if (tid < MT) tv[tid] = centf[(long)(e * MT + tid) * 4 + 3];
    __syncthreads();
    if (tid < MT) {
        const float t = tv[tid]; int r = 0;
        for (int j = 0; j < MT; ++j)
            r += (tv[j] < t || (tv[j] == t && j < tid)) ? 1 : 0;
        rk[tid] = r;
    }
    __syncthreads();
    const long cent_off = (long)BATCH * MT * TOKD;
    const long mask_off = cent_off + (long)BATCH * MT * 4;
    for (int idx = tid; idx < MT * TOKD; idx += 256) {
        const int i = idx / TOKD, t = idx % TOKD;
        const long g = ((long)e * MT + rk[i]) * TOKD + t;
        if (g < out_size) out[g] = tokf_e[(long)i * TOKD + t];
    }
    for (int idx = tid; idx < MT * 4; idx += 256) {
        const int i = idx >> 2, d = idx & 3;
        const long g = cent_off + ((long)e * MT + rk[i]) * 4 + d;
        if (g < out_size) out[g] = centf[((long)e * MT + i) * 4 + d];
    }
    for (int idx = tid; idx < MT; idx += 256) {
        const long g = mask_off + (long)e * MT + idx;
        if (g < out_size) out[g] = 1.0f;
    }
}

// ---------------------------------------------------------------------------
extern "C" void kernel_launch(void* const* d_in, const int* in_sizes, int n_in,
                              void* d_out, int out_size, void* d_ws, size_t ws_size,
                              hipStream_t stream)
{
    const float* coords = (const float*)d_in[0];
    const float* feats  = (const float*)d_in[1];
    const float* lt     = (const float*)d_in[2];
    const float* w1  = (const float*)d_in[3];  const float* b1  = (const float*)d_in[4];
    const float* w2  = (const float*)d_in[5];  const float* b2  = (const float*)d_in[6];
    const float* w3  = (const float*)d_in[7];  const float* b3  = (const float*)d_in[8];
    const float* w4  = (const float*)d_in[9];  const float* b4  = (const float*)d_in[10];
    const float* iw1 = (const float*)d_in[11]; const float* ib1 = (const float*)d_in[12];
    const float* lng = (const float*)d_in[13]; const float* lnb = (const float*)d_in[14];
    const float* iw2 = (const float*)d_in[15]; const float* ib2 = (const float*)d_in[16];
    const float* iw3 = (const float*)d_in[17]; const float* ib3 = (const float*)d_in[18];
    const float* nw1 = (const float*)d_in[19]; const float* nb1 = (const float*)d_in[20];
    const float* nw2 = (const float*)d_in[21]; const float* nb2 = (const float*)d_in[22];
    const float* noise = (const float*)d_in[23];

    // fixed ws (floats): pert + centf + knn + pooled ≈ 3.75 MB.
    // ping-pong region: 2 x ch x 768 floats; ch adaptive up to NPT.
    const size_t FIXED  = (size_t)NPT + 4096 + 16384 + (size_t)1024 * TOKD;
    const size_t perrow = 1536;
    int ch = 128;
    while (ch < NPT && (FIXED + (size_t)(ch * 2) * perrow) * 4 <= ws_size) ch <<= 1;

    float* pert   = (float*)d_ws;                       // NPT
    float* centf  = pert + NPT;                         // 1024*4
    int*   knn    = (int*)(centf + 4096);               // 16384 ints
    float* pooled = (float*)(knn + 16384);              // 1024*768
    float* bufA   = pooled + (size_t)1024 * TOKD;       // ch*768
    float* bufB   = bufA + (size_t)ch * 768;            // ch*768

    // ---- chunked MLP: features -> pert (selection chain, split-bf16 MFMA) --
    for (int ck = 0; ck < NPT / ch; ++ck) {
        const int base = ck * ch;
        l1_kernel<<<dim3(ch), dim3(256), 0, stream>>>(feats, w1, b1, bufA, base, nullptr);
        gemm_mf<<<dim3(512 / 128, ch / 128), dim3(256), 0, stream>>>(
            bufA, 256, 256, 256, nullptr, 0, w2, b2, bufB, 512, 1);
        gemm_mf<<<dim3(768 / 128, ch / 128), dim3(256), 0, stream>>>(
            bufB, 512, 512, 512, nullptr, 0, w3, b3, bufA, 768, 1);
        gemm_mf<<<dim3(768 / 128, ch / 128), dim3(256), 0, stream>>>(
            bufA, 768, 768, 768, nullptr, 0, w4, b4, bufB, 768, 0);
        gemm_mf<<<dim3(256 / 128, ch / 128), dim3(256), 0, stream>>>(
            bufB, 768, 772, 768, coords, base, iw1, ib1, bufA, 256, 1);
        ln_kernel<<<dim3(ch), dim3(256), 0, stream>>>(bufA, lng, lnb);
        gemm_mf<<<dim3(256 / 128, ch / 128), dim3(256), 0, stream>>>(
            bufA, 256, 256, 256, nullptr, 0, iw2, ib2, bufB, 256, 1);
        imp_kernel<<<dim3(ch), dim3(256), 0, stream>>>(bufB, iw3, ib3, noise, lt, pert, base);
    }

    // ---- selection + KNN ----
    topk_kernel<<<dim3(BATCH), dim3(256), 0, stream>>>(pert, coords, centf);
    knn_kernel<<<dim3(BATCH * MT), dim3(256), 0, stream>>>(coords, centf, knn);

    // ---- recompute pf for the 16384 gathered neighbor rows (chunked), pool --
    const int NBR  = BATCH * MT * KNN;   // 16384
    const int rcch = (ch < NBR) ? ch : NBR;
    for (int rc = 0; rc < NBR / rcch; ++rc) {
        l1_kernel<<<dim3(rcch), dim3(256), 0, stream>>>(feats, w1, b1, bufA, 0, knn + (size_t)rc * rcch);
        gemm_mf<<<dim3(512 / 128, rcch / 128), dim3(256), 0, stream>>>(
            bufA, 256, 256, 256, nullptr, 0, w2, b2, bufB, 512, 1);
        gemm_mf<<<dim3(768 / 128, rcch / 128), dim3(256), 0, stream>>>(
            bufB, 512, 512, 512, nullptr, 0, w3, b3, bufA, 768, 1);
        gemm_mf<<<dim3(768 / 128, rcch / 128), dim3(256), 0, stream>>>(
            bufA, 768, 768, 768, nullptr, 0, w4, b4, bufB, 768, 0);
        pool_kernel<<<dim3(rcch / KNN), dim3(256), 0, stream>>>(
            bufB, pooled + (size_t)rc * (rcch / KNN) * TOKD);
    }

    // ---- token MLP (1024x768) + emit ----
    if (ch >= 1024) {
        float* t1 = bufA, *tokf = bufB;
        gemm_mf<<<dim3(768 / 128, 1024 / 128), dim3(256), 0, stream>>>(
            pooled, 768, 768, 768, nullptr, 0, nw1, nb1, t1, 768, 1);
        gemm_mf<<<dim3(768 / 128, 1024 / 128), dim3(256), 0, stream>>>(
            t1, 768, 768, 768, nullptr, 0, nw2, nb2, tokf, 768, 0);
        for (int e = 0; e < BATCH; ++e)
            emit_kernel<<<dim3(1), dim3(256), 0, stream>>>(
                centf, tokf + (size_t)e * MT * TOKD, e, (float*)d_out, (long)out_size);
    } else {
        for (int e = 0; e < BATCH; ++e) {
            gemm_mf<<<dim3(768 / 128, 1), dim3(256), 0, stream>>>(
                pooled + (size_t)e * MT * TOKD, 768, 768, 768, nullptr, 0,
                nw1, nb1, bufA, 768, 1);
            gemm_mf<<<dim3(768 / 128, 1), dim3(256), 0, stream>>>(
                bufA, 768, 768, 768, nullptr, 0, nw2, nb2, bufB, 768, 0);
            emit_kernel<<<dim3(1), dim3(256), 0, stream>>>(
                centf, bufB, e, (float*)d_out, (long)out_size);
        }
    }
}

// Round 10
// 3679.287 us; speedup vs baseline: 2.1558x; 1.2180x over previous
//
#include <hip/hip_runtime.h>
#include <hip/hip_bf16.h>

// GumbelSoftmaxTokenizer: B=8, P=16384, FEAT=6, TOK=768, MT=128, K=16, IH=256
// All inputs float32; output buffer float32 (tokens, cents, masks concat).
#define NPT   131072      // B*P
#define BATCH 8
#define PPE   16384
#define MT    128
#define KNN   16
#define TOKD  768

typedef short bf16x8 __attribute__((ext_vector_type(8)));
typedef float f32x4  __attribute__((ext_vector_type(4)));

#define LDK 40   // LDS row stride in shorts (80B rows; 64B data + 16B pad)

__device__ __forceinline__ unsigned pack_hi(unsigned u0, unsigned u1) {
    return (u0 >> 16) | (u1 & 0xFFFF0000u);   // bf16 pair (e0,e1), truncated
}

// ---------------------------------------------------------------------------
// Weight pre-convert: W(KxN f32) -> Wt_hi/Wt_lo [N][Kpad] bf16 (transposed,
// zero-padded to Kpad). One block per n; coalesced writes along k.
// ---------------------------------------------------------------------------
__global__ __launch_bounds__(256) void wsplit_kernel(const float* __restrict__ W,
                                                     int K, int N, int Kpad,
                                                     short* __restrict__ hi,
                                                     short* __restrict__ lo)
{
    const int n = blockIdx.x;
    for (int k = threadIdx.x; k < Kpad; k += 256) {
        short h = 0, l = 0;
        if (k < K) {
            const float x = W[(long)k * N + n];
            const unsigned u = __float_as_uint(x);
            h = (short)(u >> 16);
            const float r = x - __uint_as_float(u & 0xFFFF0000u);
            l = (short)(__float_as_uint(r) >> 16);
        }
        hi[(long)n * Kpad + k] = h;
        lo[(long)n * Kpad + k] = l;
    }
}

// ---------------------------------------------------------------------------
// L1: h1[r] = relu(features[row(r)] @ w1(6x256) + b1); row = base+r or
// gather[r] (clamped) for the KNN-recompute pass.
// ---------------------------------------------------------------------------
__global__ __launch_bounds__(256) void l1_kernel(const float* __restrict__ f,
                                                 const float* __restrict__ w1,
                                                 const float* __restrict__ b1,
                                                 float* __restrict__ h1,
                                                 int base,
                                                 const int* __restrict__ gather)
{
    const int r = blockIdx.x, n = threadIdx.x;
    int row = gather ? gather[r] : (base + r);
    row = (row < 0) ? 0 : ((row >= NPT) ? (NPT - 1) : row);
    __shared__ float fs[6];
    if (threadIdx.x < 6) fs[threadIdx.x] = f[(long)row * 6 + threadIdx.x];
    __syncthreads();
    float acc = b1[n];
#pragma unroll
    for (int k = 0; k < 6; ++k) acc += fs[k] * w1[k * 256 + n];
    h1[(long)r * 256 + n] = fmaxf(acc, 0.f);
}

// ---------------------------------------------------------------------------
// Split-bf16 MFMA GEMM (3-product): C = [relu](A(MxK,f32) @ W + bias) where
// W is pre-converted to transposed bf16 hi/lo planes [N][Kpad]. A is split
// to hi/lo at stage time. Products hh + hl + lh (ll dropped: ~2^-16 rel).
// Block 128x128, BK=32, 256 thr = 4 waves; wave = 32 rows x 128 cols as
// 2x8 16x16 C-tiles, 48 mfma_f32_16x16x32_bf16 per wave per k-step.
// A cols K1..K-1 from coords[:,1:5] rows (a2base+r) when A2c != null.
// M,N multiples of 128. LDS 40,960B -> 3 blocks/CU.
// ---------------------------------------------------------------------------
__global__ __launch_bounds__(256) void gemm_mf(
    const float* __restrict__ A, int lda, int K, int K1,
    const float* __restrict__ A2c, int a2base,
    const short* __restrict__ Wth, const short* __restrict__ Wtl, int Kpad,
    const float* __restrict__ bias,
    float* __restrict__ C, int N, int relu)
{
    __shared__ short Ah[128 * LDK];
    __shared__ short Al[128 * LDK];
    __shared__ short Bh[128 * LDK];
    __shared__ short Bl[128 * LDK];
    const int tid  = threadIdx.x;
    const int row0 = blockIdx.y << 7, col0 = blockIdx.x << 7;
    const int wave = tid >> 6, lane = tid & 63;
    const int q = lane >> 4, l16 = lane & 15;

    f32x4 acc[2][8];
#pragma unroll
    for (int mt = 0; mt < 2; ++mt)
#pragma unroll
        for (int nt = 0; nt < 8; ++nt)
            acc[mt][nt] = (f32x4){0.f, 0.f, 0.f, 0.f};

    const int bn = tid >> 1, bhf = (tid & 1) << 4;   // B copy: n-row, k-half

    const int nk = Kpad >> 5;
    for (int t = 0; t < nk; ++t) {
        const int k0 = t << 5;
        // ---- stage A: 128 rows x 32 k (f32 -> hi/lo bf16), 4 float4/thread
#pragma unroll
        for (int s = 0; s < 4; ++s) {
            const int l  = (s << 8) + tid;      // 0..1023
            const int m  = l >> 3;
            const int k4 = (l & 7) << 2;
            const int kg = k0 + k4;
            const int r  = row0 + m;
            float4 v;
            if (kg + 3 < K1) {
                v = *(const float4*)&A[(long)r * lda + kg];
            } else {
                float tmp[4];
#pragma unroll
                for (int qq = 0; qq < 4; ++qq) {
                    const int kq = kg + qq;
                    float x = 0.f;
                    if (kq < K1)      x = A[(long)r * lda + kq];
                    else if (kq < K)  x = A2c[(long)(a2base + r) * 5 + 1 + (kq - K1)];
                    tmp[qq] = x;
                }
                v = make_float4(tmp[0], tmp[1], tmp[2], tmp[3]);
            }
            const unsigned u0 = __float_as_uint(v.x), u1 = __float_as_uint(v.y);
            const unsigned u2 = __float_as_uint(v.z), u3 = __float_as_uint(v.w);
            const unsigned r0 = __float_as_uint(v.x - __uint_as_float(u0 & 0xFFFF0000u));
            const unsigned r1 = __float_as_uint(v.y - __uint_as_float(u1 & 0xFFFF0000u));
            const unsigned r2 = __float_as_uint(v.z - __uint_as_float(u2 & 0xFFFF0000u));
            const unsigned r3 = __float_as_uint(v.w - __uint_as_float(u3 & 0xFFFF0000u));
            *(int2*)&Ah[m * LDK + k4] = make_int2((int)pack_hi(u0, u1), (int)pack_hi(u2, u3));
            *(int2*)&Al[m * LDK + k4] = make_int2((int)pack_hi(r0, r1), (int)pack_hi(r2, r3));
        }
        // ---- stage B: pure vector copies from pre-converted planes
        {
            const long src = (long)(col0 + bn) * Kpad + k0 + bhf;
            *(int4*)&Bh[bn * LDK + bhf + 0] = *(const int4*)&Wth[src + 0];
            *(int4*)&Bh[bn * LDK + bhf + 8] = *(const int4*)&Wth[src + 8];
            *(int4*)&Bl[bn * LDK + bhf + 0] = *(const int4*)&Wtl[src + 0];
            *(int4*)&Bl[bn * LDK + bhf + 8] = *(const int4*)&Wtl[src + 8];
        }
        __syncthreads();
        // ---- MFMA: wave rows [wave*32, +32), 2 m-tiles x 8 n-tiles
        bf16x8 ah[2], al[2];
#pragma unroll
        for (int mt = 0; mt < 2; ++mt) {
            const int mrow = (wave << 5) + (mt << 4) + l16;
            ah[mt] = *(const bf16x8*)&Ah[mrow * LDK + (q << 3)];
            al[mt] = *(const bf16x8*)&Al[mrow * LDK + (q << 3)];
        }
#pragma unroll
        for (int nt = 0; nt < 8; ++nt) {
            const int ncol = (nt << 4) + l16;
            const bf16x8 bh = *(const bf16x8*)&Bh[ncol * LDK + (q << 3)];
            const bf16x8 bl = *(const bf16x8*)&Bl[ncol * LDK + (q << 3)];
#pragma unroll
            for (int mt = 0; mt < 2; ++mt) {
                acc[mt][nt] = __builtin_amdgcn_mfma_f32_16x16x32_bf16(ah[mt], bh, acc[mt][nt], 0, 0, 0);
                acc[mt][nt] = __builtin_amdgcn_mfma_f32_16x16x32_bf16(ah[mt], bl, acc[mt][nt], 0, 0, 0);
                acc[mt][nt] = __builtin_amdgcn_mfma_f32_16x16x32_bf16(al[mt], bh, acc[mt][nt], 0, 0, 0);
            }
        }
        __syncthreads();
    }
    // ---- epilogue: C/D layout col=lane&15, row=quad*4+reg
#pragma unroll
    for (int mt = 0; mt < 2; ++mt)
#pragma unroll
        for (int nt = 0; nt < 8; ++nt) {
            const int col = col0 + (nt << 4) + l16;
            const float bs = bias[col];
#pragma unroll
            for (int rg = 0; rg < 4; ++rg) {
                const int row = row0 + (wave << 5) + (mt << 4) + (q << 2) + rg;
                float v = acc[mt][nt][rg] + bs;
                if (relu) v = fmaxf(v, 0.f);
                C[(long)row * N + col] = v;
            }
        }
}

// ---------------------------------------------------------------------------
// LayerNorm (in place) over 256 features/row
// ---------------------------------------------------------------------------
__global__ __launch_bounds__(256) void ln_kernel(float* __restrict__ z,
                                                 const float* __restrict__ g,
                                                 const float* __restrict__ b)
{
    const int r = blockIdx.x, tid = threadIdx.x;
    float x = z[(long)r * 256 + tid];
    __shared__ float part[4];
    __shared__ float mu_s, den_s;
    float s = x;
#pragma unroll
    for (int off = 32; off; off >>= 1) s += __shfl_down(s, off);
    if ((tid & 63) == 0) part[tid >> 6] = s;
    __syncthreads();
    if (tid == 0) mu_s = (part[0] + part[1] + part[2] + part[3]) * (1.f / 256.f);
    __syncthreads();
    const float mu = mu_s;
    const float d = x - mu;
    float s2 = d * d;
#pragma unroll
    for (int off = 32; off; off >>= 1) s2 += __shfl_down(s2, off);
    if ((tid & 63) == 0) part[tid >> 6] = s2;
    __syncthreads();
    if (tid == 0)
        den_s = sqrtf((part[0] + part[1] + part[2] + part[3]) * (1.f / 256.f) + 1e-5f);
    __syncthreads();
    z[(long)r * 256 + tid] = d / den_s * g[tid] + b[tid];
}

// ---------------------------------------------------------------------------
// imp = z2 @ iw3 + ib3 ; pert = (imp + noise)/max(exp(lt),0.1)
// ---------------------------------------------------------------------------
__global__ __launch_bounds__(256) void imp_kernel(const float* __restrict__ z2,
                                                  const float* __restrict__ iw3,
                                                  const float* __restrict__ ib3,
                                                  const float* __restrict__ noise,
                                                  const float* __restrict__ lt,
                                                  float* __restrict__ pert,
                                                  int base)
{
    const int r = blockIdx.x, tid = threadIdx.x;
    float v = z2[(long)r * 256 + tid] * iw3[tid];
    __shared__ float part[4];
#pragma unroll
    for (int off = 32; off; off >>= 1) v += __shfl_down(v, off);
    if ((tid & 63) == 0) part[tid >> 6] = v;
    __syncthreads();
    if (tid == 0) {
        const float imp  = part[0] + part[1] + part[2] + part[3] + ib3[0];
        const float temp = fmaxf(expf(lt[0]), 0.1f);
        pert[base + r] = (imp + noise[base + r]) / temp;
    }
}

// ---------------------------------------------------------------------------
// top-128 per event via 4-pass radix-select (order-preserving uint map),
// exact tie handling (lowest indices first), 128-elem bitonic sort by
// (value desc, index asc) = jax top_k order.
// ---------------------------------------------------------------------------
__device__ __forceinline__ unsigned fmap(float f) {
    unsigned x = __float_as_uint(f);
    return (x & 0x80000000u) ? ~x : (x | 0x80000000u);
}

__global__ __launch_bounds__(256) void topk_kernel(const float* __restrict__ pert,
                                                   const float* __restrict__ coords,
                                                   float* __restrict__ centf)
{
    const int e = blockIdx.x, tid = threadIdx.x;
    const int base = e * PPE;
    __shared__ unsigned hist[256];
    __shared__ unsigned sh_prefix;
    __shared__ int sh_need;
    unsigned prefix = 0, known = 0;
    int need = MT;
    for (int shift = 24; shift >= 0; shift -= 8) {
        hist[tid] = 0;
        __syncthreads();
        for (int i = tid; i < PPE; i += 256) {
            const unsigned u = fmap(pert[base + i]);
            if ((u & known) == prefix) atomicAdd(&hist[(u >> shift) & 255u], 1u);
        }
        __syncthreads();
        if (tid == 0) {
            int cum = 0, b = 255;
            for (; b > 0; --b) { cum += (int)hist[b]; if (cum >= need) break; }
            if (cum < need) { cum += (int)hist[0]; b = 0; }
            sh_need   = need - (cum - (int)hist[b]);
            sh_prefix = prefix | ((unsigned)b << shift);
        }
        __syncthreads();
        need   = sh_need;
        prefix = sh_prefix;
        known |= (255u << shift);
        __syncthreads();
    }
    const unsigned T = prefix;
    const int need_eq = need;

    __shared__ unsigned selu[MT];
    __shared__ int      seli[MT];
    __shared__ int cgt, ceq;
    __shared__ int eqbuf[256];
    if (tid == 0) { cgt = 0; ceq = 0; }
    __syncthreads();
    for (int i = tid; i < PPE; i += 256) {
        const unsigned u = fmap(pert[base + i]);
        if (u > T)       { int p = atomicAdd(&cgt, 1); selu[p] = u; seli[p] = i; }
        else if (u == T) { int p = atomicAdd(&ceq, 1); if (p < 256) eqbuf[p] = i; }
    }
    __syncthreads();
    const int ngt = cgt;
    if (ceq <= 256) {
        if (tid >= ceq) eqbuf[tid] = 0x7FFFFFFF;
        __syncthreads();
        for (int k = 2; k <= 256; k <<= 1)
            for (int j = k >> 1; j > 0; j >>= 1) {
                const int l = tid ^ j;
                if (l > tid) {
                    const int a = eqbuf[tid], b = eqbuf[l];
                    const bool up = ((tid & k) == 0);
                    if (up ? (a > b) : (a < b)) { eqbuf[tid] = b; eqbuf[l] = a; }
                }
                __syncthreads();
            }
        if (tid < need_eq) { selu[ngt + tid] = T; seli[ngt + tid] = eqbuf[tid]; }
    } else if (tid == 0) {
        int cur = -1;
        for (int qq = 0; qq < need_eq; ++qq) {
            int best = 0x7FFFFFFF;
            for (int i = 0; i < PPE; ++i)
                if (i > cur && fmap(pert[base + i]) == T && i < best) best = i;
            selu[ngt + qq] = T; seli[ngt + qq] = best; cur = best;
        }
    }
    __syncthreads();
    __shared__ unsigned long long key[MT];
    if (tid < MT)
        key[tid] = ((unsigned long long)selu[tid] << 32) | (unsigned)(~seli[tid]);
    __syncthreads();
    for (int k = 2; k <= MT; k <<= 1)
        for (int j = k >> 1; j > 0; j >>= 1) {
            if (tid < MT) {
                const int l = tid ^ j;
                if (l > tid) {
                    const unsigned long long a = key[tid], b = key[l];
                    const bool up = ((tid & k) == 0);
                    if (up ? (a < b) : (a > b)) { key[tid] = b; key[l] = a; }
                }
            }
            __syncthreads();
        }
    if (tid < MT) {
        const int idx = (int)(~(unsigned)(key[tid] & 0xFFFFFFFFu));
        const long cb = (long)(base + idx) * 5;
        centf[(long)(e * MT + tid) * 4 + 0] = coords[cb + 1];
        centf[(long)(e * MT + tid) * 4 + 1] = coords[cb + 2];
        centf[(long)(e * MT + tid) * 4 + 2] = coords[cb + 3];
        centf[(long)(e * MT + tid) * 4 + 3] = coords[cb + 4];
    }
}

// ---------------------------------------------------------------------------
// per (event,centroid): 16-NN over 16384 points (smallest d2, ties -> lower
// index = jax top_k(-d2)). Sequential 4-term fp32 sum matches the np ref.
// ---------------------------------------------------------------------------
__global__ __launch_bounds__(256) void knn_kernel(const float* __restrict__ coords,
                                                  const float* __restrict__ centf,
                                                  int* __restrict__ knn_idx)
{
    const int blk = blockIdx.x;
    const int e = blk >> 7;
    const int tid = threadIdx.x;
    const int base = e * PPE;
    const float c0 = centf[(long)blk * 4 + 0];
    const float c1 = centf[(long)blk * 4 + 1];
    const float c2 = centf[(long)blk * 4 + 2];
    const float c3 = centf[(long)blk * 4 + 3];
    float ld[KNN]; int li[KNN];
#pragma unroll
    for (int i = 0; i < KNN; ++i) { ld[i] = 3.4e38f; li[i] = 0x7FFFFFFF; }
    for (int p = tid; p < PPE; p += 256) {
        const long cb = (long)(base + p) * 5;
        const float x0 = coords[cb + 1];
        const float x1 = coords[cb + 2];
        const float x2 = coords[cb + 3];
        const float x3 = coords[cb + 4];
        const float q0 = __fmul_rn(c0 - x0, c0 - x0);
        const float q1 = __fmul_rn(c1 - x1, c1 - x1);
        const float q2 = __fmul_rn(c2 - x2, c2 - x2);
        const float q3 = __fmul_rn(c3 - x3, c3 - x3);
        const float d  = __fadd_rn(__fadd_rn(__fadd_rn(q0, q1), q2), q3);
        if (d < ld[KNN - 1] || (d == ld[KNN - 1] && p < li[KNN - 1])) {
            int j = KNN - 1;
            while (j > 0 && (d < ld[j - 1] || (d == ld[j - 1] && p < li[j - 1]))) {
                ld[j] = ld[j - 1]; li[j] = li[j - 1]; --j;
            }
            ld[j] = d; li[j] = p;
        }
    }
    __shared__ float hv[256];
    __shared__ int   hi2[256];
    __shared__ int   ho[256];
    int ptr = 0;
    for (int r = 0; r < KNN; ++r) {
        hv[tid]  = (ptr < KNN) ? ld[ptr] : 3.4e38f;
        hi2[tid] = (ptr < KNN) ? li[ptr] : 0x7FFFFFFF;
        ho[tid]  = tid;
        __syncthreads();
        for (int s = 128; s > 0; s >>= 1) {
            if (tid < s) {
                const float v2 = hv[tid + s]; const int i2 = hi2[tid + s];
                if (v2 < hv[tid] || (v2 == hv[tid] && i2 < hi2[tid])) {
                    hv[tid] = v2; hi2[tid] = i2; ho[tid] = ho[tid + s];
                }
            }
            __syncthreads();
        }
        if (tid == ho[0]) ptr++;
        if (tid == 0) {
            int ix = hi2[0];
            ix = (ix < 0) ? 0 : ((ix >= PPE) ? (PPE - 1) : ix);
            knn_idx[blk * KNN + r] = base + ix;
        }
        __syncthreads();
    }
}

// ---------------------------------------------------------------------------
// pooled[blk][t] = max over 16 recomputed-pf neighbor rows (chunk layout)
// ---------------------------------------------------------------------------
__global__ __launch_bounds__(256) void pool_kernel(const float* __restrict__ pf_nbr,
                                                   float* __restrict__ pooled)
{
    const int blk = blockIdx.x, tid = threadIdx.x;
    for (int t = tid; t < TOKD; t += 256) {
        float mx = -3.4e38f;
#pragma unroll
        for (int j = 0; j < KNN; ++j)
            mx = fmaxf(mx, pf_nbr[(long)(blk * KNN + j) * TOKD + t]);
        pooled[(long)blk * TOKD + t] = mx;
    }
}

// ---------------------------------------------------------------------------
// per event: stable rank by cent[:,3] asc + emit tokens/cents/masks as FP32.
// ---------------------------------------------------------------------------
__global__ __launch_bounds__(256) void emit_kernel(const float* __restrict__ centf,
                                                   const float* __restrict__ tokf_e,
                                                   int e, float* __restrict__ out,
                                                   long out_size)
{
    const int tid = threadIdx.x;
    __shared__ float tv[MT];
    __shared__ int   rk[MT];
    if (tid < MT) tv[tid] = centf[(long)(e * MT + tid) * 4 + 3];
    __syncthreads();
    if (tid < MT) {
        const float t = tv[tid]; int r = 0;
        for (int j = 0; j < MT; ++j)
            r += (tv[j] < t || (tv[j] == t && j < tid)) ? 1 : 0;
        rk[tid] = r;
    }
    __syncthreads();
    const long cent_off = (long)BATCH * MT * TOKD;
    const long mask_off = cent_off + (long)BATCH * MT * 4;
    for (int idx = tid; idx < MT * TOKD; idx += 256) {
        const int i = idx / TOKD, t = idx % TOKD;
        const long g = ((long)e * MT + rk[i]) * TOKD + t;
        if (g < out_size) out[g] = tokf_e[(long)i * TOKD + t];
    }
    for (int idx = tid; idx < MT * 4; idx += 256) {
        const int i = idx >> 2, d = idx & 3;
        const long g = cent_off + ((long)e * MT + rk[i]) * 4 + d;
        if (g < out_size) out[g] = centf[((long)e * MT + i) * 4 + d];
    }
    for (int idx = tid; idx < MT; idx += 256) {
        const long g = mask_off + (long)e * MT + idx;
        if (g < out_size) out[g] = 1.0f;
    }
}

// ---------------------------------------------------------------------------
extern "C" void kernel_launch(void* const* d_in, const int* in_sizes, int n_in,
                              void* d_out, int out_size, void* d_ws, size_t ws_size,
                              hipStream_t stream)
{
    const float* coords = (const float*)d_in[0];
    const float* feats  = (const float*)d_in[1];
    const float* lt     = (const float*)d_in[2];
    const float* w1  = (const float*)d_in[3];  const float* b1  = (const float*)d_in[4];
    const float* w2  = (const float*)d_in[5];  const float* b2  = (const float*)d_in[6];
    const float* w3  = (const float*)d_in[7];  const float* b3  = (const float*)d_in[8];
    const float* w4  = (const float*)d_in[9];  const float* b4  = (const float*)d_in[10];
    const float* iw1 = (const float*)d_in[11]; const float* ib1 = (const float*)d_in[12];
    const float* lng = (const float*)d_in[13]; const float* lnb = (const float*)d_in[14];
    const float* iw2 = (const float*)d_in[15]; const float* ib2 = (const float*)d_in[16];
    const float* iw3 = (const float*)d_in[17]; const float* ib3 = (const float*)d_in[18];
    const float* nw1 = (const float*)d_in[19]; const float* nb1 = (const float*)d_in[20];
    const float* nw2 = (const float*)d_in[21]; const float* nb2 = (const float*)d_in[22];
    const float* noise = (const float*)d_in[23];

    // ---- ws layout ----
    // floats: pert(NPT) + centf(4096) + knn(16384 int) + pooled(1024*768)
    // shorts: weight planes (hi+lo per weight, transposed [N][Kpad])
    // floats: bufA/bufB ping-pong (2 x ch x 768)
    const size_t FIXED_FL = (size_t)NPT + 4096 + 16384 + (size_t)1024 * TOKD;
    // plane sizes in shorts: [N][Kpad]
    const size_t s_w2 = 512 * 256,  s_w3 = 768 * 512,  s_w4 = 768 * 768;
    const size_t s_i1 = 256 * 800,  s_i2 = 256 * 256;
    const size_t s_n1 = 768 * 768,  s_n2 = 768 * 768;
    const size_t WTOT = 2 * (s_w2 + s_w3 + s_w4 + s_i1 + s_i2 + s_n1 + s_n2);
    const size_t BASE_BYTES = FIXED_FL * 4 + WTOT * 2;

    int ch = 128;
    while (ch < NPT && BASE_BYTES + (size_t)(ch * 2) * 2 * 768 * 4 * 2 <= ws_size * 2
           && BASE_BYTES + (size_t)(ch * 2) * 768 * 2 * 4 <= ws_size) ch <<= 1;

    float* pert   = (float*)d_ws;                       // NPT
    float* centf  = pert + NPT;                         // 1024*4
    int*   knn    = (int*)(centf + 4096);               // 16384 ints
    float* pooled = (float*)(knn + 16384);              // 1024*768
    short* wsp    = (short*)(pooled + (size_t)1024 * TOKD);
    short* w2h = wsp;            short* w2l = w2h + s_w2;
    short* w3h = w2l + s_w2;     short* w3l = w3h + s_w3;
    short* w4h = w3l + s_w3;     short* w4l = w4h + s_w4;
    short* i1h = w4l + s_w4;     short* i1l = i1h + s_i1;
    short* i2h = i1l + s_i1;     short* i2l = i2h + s_i2;
    short* n1h = i2l + s_i2;     short* n1l = n1h + s_n1;
    short* n2h = n1l + s_n1;     short* n2l = n2h + s_n2;
    float* bufA = (float*)(((size_t)(n2l + s_n2) + 15) & ~(size_t)15);  // align 16B
    float* bufB = bufA + (size_t)ch * 768;

    // ---- pre-convert weights (once per launch; deterministic) ----
    wsplit_kernel<<<dim3(512), dim3(256), 0, stream>>>(w2, 256, 512, 256, w2h, w2l);
    wsplit_kernel<<<dim3(768), dim3(256), 0, stream>>>(w3, 512, 768, 512, w3h, w3l);
    wsplit_kernel<<<dim3(768), dim3(256), 0, stream>>>(w4, 768, 768, 768, w4h, w4l);
    wsplit_kernel<<<dim3(256), dim3(256), 0, stream>>>(iw1, 772, 256, 800, i1h, i1l);
    wsplit_kernel<<<dim3(256), dim3(256), 0, stream>>>(iw2, 256, 256, 256, i2h, i2l);
    wsplit_kernel<<<dim3(768), dim3(256), 0, stream>>>(nw1, 768, 768, 768, n1h, n1l);
    wsplit_kernel<<<dim3(768), dim3(256), 0, stream>>>(nw2, 768, 768, 768, n2h, n2l);

    // ---- chunked MLP: features -> pert (selection chain) ----
    for (int ck = 0; ck < NPT / ch; ++ck) {
        const int base = ck * ch;
        l1_kernel<<<dim3(ch), dim3(256), 0, stream>>>(feats, w1, b1, bufA, base, nullptr);
        gemm_mf<<<dim3(512 / 128, ch / 128), dim3(256), 0, stream>>>(
            bufA, 256, 256, 256, nullptr, 0, w2h, w2l, 256, b2, bufB, 512, 1);
        gemm_mf<<<dim3(768 / 128, ch / 128), dim3(256), 0, stream>>>(
            bufB, 512, 512, 512, nullptr, 0, w3h, w3l, 512, b3, bufA, 768, 1);
        gemm_mf<<<dim3(768 / 128, ch / 128), dim3(256), 0, stream>>>(
            bufA, 768, 768, 768, nullptr, 0, w4h, w4l, 768, b4, bufB, 768, 0);
        gemm_mf<<<dim3(256 / 128, ch / 128), dim3(256), 0, stream>>>(
            bufB, 768, 772, 768, coords, base, i1h, i1l, 800, ib1, bufA, 256, 1);
        ln_kernel<<<dim3(ch), dim3(256), 0, stream>>>(bufA, lng, lnb);
        gemm_mf<<<dim3(256 / 128, ch / 128), dim3(256), 0, stream>>>(
            bufA, 256, 256, 256, nullptr, 0, i2h, i2l, 256, ib2, bufB, 256, 1);
        imp_kernel<<<dim3(ch), dim3(256), 0, stream>>>(bufB, iw3, ib3, noise, lt, pert, base);
    }

    // ---- selection + KNN ----
    topk_kernel<<<dim3(BATCH), dim3(256), 0, stream>>>(pert, coords, centf);
    knn_kernel<<<dim3(BATCH * MT), dim3(256), 0, stream>>>(coords, centf, knn);

    // ---- recompute pf for the 16384 gathered neighbor rows (chunked), pool --
    const int NBR  = BATCH * MT * KNN;   // 16384
    const int rcch = (ch < NBR) ? ch : NBR;
    for (int rc = 0; rc < NBR / rcch; ++rc) {
        l1_kernel<<<dim3(rcch), dim3(256), 0, stream>>>(feats, w1, b1, bufA, 0, knn + (size_t)rc * rcch);
        gemm_mf<<<dim3(512 / 128, rcch / 128), dim3(256), 0, stream>>>(
            bufA, 256, 256, 256, nullptr, 0, w2h, w2l, 256, b2, bufB, 512, 1);
        gemm_mf<<<dim3(768 / 128, rcch / 128), dim3(256), 0, stream>>>(
            bufB, 512, 512, 512, nullptr, 0, w3h, w3l, 512, b3, bufA, 768, 1);
        gemm_mf<<<dim3(768 / 128, rcch / 128), dim3(256), 0, stream>>>(
            bufA, 768, 768, 768, nullptr, 0, w4h, w4l, 768, b4, bufB, 768, 0);
        pool_kernel<<<dim3(rcch / KNN), dim3(256), 0, stream>>>(
            bufB, pooled + (size_t)rc * (rcch / KNN) * TOKD);
    }

    // ---- token MLP (1024x768) + emit ----
    if (ch >= 1024) {
        float* t1 = bufA, *tokf = bufB;
        gemm_mf<<<dim3(768 / 128, 1024 / 128), dim3(256), 0, stream>>>(
            pooled, 768, 768, 768, nullptr, 0, n1h, n1l, 768, nb1, t1, 768, 1);
        gemm_mf<<<dim3(768 / 128, 1024 / 128), dim3(256), 0, stream>>>(
            t1, 768, 768, 768, nullptr, 0, n2h, n2l, 768, nb2, tokf, 768, 0);
        for (int e = 0; e < BATCH; ++e)
            emit_kernel<<<dim3(1), dim3(256), 0, stream>>>(
                centf, tokf + (size_t)e * MT * TOKD, e, (float*)d_out, (long)out_size);
    } else {
        for (int e = 0; e < BATCH; ++e) {
            gemm_mf<<<dim3(768 / 128, 1), dim3(256), 0, stream>>>(
                pooled + (size_t)e * MT * TOKD, 768, 768, 768, nullptr, 0,
                n1h, n1l, 768, nb1, bufA, 768, 1);
            gemm_mf<<<dim3(768 / 128, 1), dim3(256), 0, stream>>>(
                bufA, 768, 768, 768, nullptr, 0, n2h, n2l, 768, nb2, bufB, 768, 0);
            emit_kernel<<<dim3(1), dim3(256), 0, stream>>>(
                centf, bufB, e, (float*)d_out, (long)out_size);
        }
    }
}

// Round 11
// 2613.012 us; speedup vs baseline: 3.0355x; 1.4081x over previous
//
#include <hip/hip_runtime.h>
#include <hip/hip_bf16.h>

// GumbelSoftmaxTokenizer: B=8, P=16384, FEAT=6, TOK=768, MT=128, K=16, IH=256
// All inputs float32; output buffer float32 (tokens, cents, masks concat).
#define NPT   131072      // B*P
#define BATCH 8
#define PPE   16384
#define MT    128
#define KNN   16
#define TOKD  768

typedef short bf16x8 __attribute__((ext_vector_type(8)));
typedef float f32x4  __attribute__((ext_vector_type(4)));

#define LDK 40   // LDS row stride in shorts (80B rows)

__device__ __forceinline__ unsigned pack_hi(unsigned u0, unsigned u1) {
    return (u0 >> 16) | (u1 & 0xFFFF0000u);   // bf16 pair (e0,e1), truncated
}
__device__ __forceinline__ void split1(float x, short& h, short& l) {
    const unsigned u = __float_as_uint(x);
    h = (short)(u >> 16);
    const float r = x - __uint_as_float(u & 0xFFFF0000u);
    l = (short)(__float_as_uint(r) >> 16);
}

// ---------------------------------------------------------------------------
// Weight pre-convert: W(KxN f32) -> hi/lo [N][Kpad] bf16 (transposed, padded)
// ---------------------------------------------------------------------------
__global__ __launch_bounds__(256) void wsplit_kernel(const float* __restrict__ W,
                                                     int K, int N, int Kpad,
                                                     short* __restrict__ hi,
                                                     short* __restrict__ lo)
{
    const int n = blockIdx.x;
    for (int k = threadIdx.x; k < Kpad; k += 256) {
        short h = 0, l = 0;
        if (k < K) split1(W[(long)k * N + n], h, l);
        hi[(long)n * Kpad + k] = h;
        lo[(long)n * Kpad + k] = l;
    }
}

// ---------------------------------------------------------------------------
// L1: h1 = relu(features @ w1 + b1) -> split planes [r][256]
// ---------------------------------------------------------------------------
__global__ __launch_bounds__(256) void l1_kernel(const float* __restrict__ f,
                                                 const float* __restrict__ w1,
                                                 const float* __restrict__ b1,
                                                 short* __restrict__ hp,
                                                 short* __restrict__ lp,
                                                 int base,
                                                 const int* __restrict__ gather)
{
    const int r = blockIdx.x, n = threadIdx.x;
    int row = gather ? gather[r] : (base + r);
    row = (row < 0) ? 0 : ((row >= NPT) ? (NPT - 1) : row);
    __shared__ float fs[6];
    if (threadIdx.x < 6) fs[threadIdx.x] = f[(long)row * 6 + threadIdx.x];
    __syncthreads();
    float acc = b1[n];
#pragma unroll
    for (int k = 0; k < 6; ++k) acc += fs[k] * w1[k * 256 + n];
    acc = fmaxf(acc, 0.f);
    short h, l; split1(acc, h, l);
    hp[(long)r * 256 + n] = h;
    lp[(long)r * 256 + n] = l;
}

// ---------------------------------------------------------------------------
// a2fill: plane cols 768..799 of the pf planes (Kpad=800): coords split for
// 768..771, zeros for the pad.
// ---------------------------------------------------------------------------
__global__ __launch_bounds__(256) void a2fill_kernel(const float* __restrict__ coords,
                                                     int base, int ch,
                                                     short* __restrict__ hp,
                                                     short* __restrict__ lp)
{
    const int idx = blockIdx.x * 256 + threadIdx.x;
    if (idx >= ch * 32) return;
    const int r = idx >> 5, c = idx & 31;
    short h = 0, l = 0;
    if (c < 4) split1(coords[(long)(base + r) * 5 + 1 + c], h, l);
    hp[(long)r * 800 + 768 + c] = h;
    lp[(long)r * 800 + 768 + c] = l;
}

// ---------------------------------------------------------------------------
// Split-bf16 MFMA GEMM (3-product, hh+hl+lh): C = [relu](A @ W + bias).
// A: split planes [M][Kpad] (Aph/Apl) OR fp32 [M][Kpad] (Afp, converted at
// stage). B: pre-split planes [N][Kpad]. Out: fp32 (Cf) and/or split planes
// (Cph/Cpl, stride KpadOut). Block 128x128, BK=32, 4 waves x (32x128).
// XCD-congruent swizzle: all col-blocks of a row-block share id%8 within an
// 8-row supergroup -> same XCD, temporally adjacent -> A L2 reuse.
// M,N multiples of 128; Kpad multiple of 32.
// ---------------------------------------------------------------------------
__global__ __launch_bounds__(256) void gemm_mf(
    const short* __restrict__ Aph, const short* __restrict__ Apl,
    const float* __restrict__ Afp, int Kpad,
    const short* __restrict__ Wth, const short* __restrict__ Wtl,
    const float* __restrict__ bias,
    short* __restrict__ Cph, short* __restrict__ Cpl, int KpadOut,
    float* __restrict__ Cf,
    int N, int relu)
{
    __shared__ short Ah[128 * LDK];
    __shared__ short Al[128 * LDK];
    __shared__ short Bh[128 * LDK];
    __shared__ short Bl[128 * LDK];
    const int tid = threadIdx.x;
    // ---- swizzle
    int rowb, colb;
    {
        const int ncol = gridDim.x, nrow = gridDim.y;
        if ((nrow & 7) == 0) {
            const int id  = blockIdx.y * ncol + blockIdx.x;
            const int sgs = ncol << 3;
            const int sg = id / sgs, wi = id % sgs;
            rowb = (sg << 3) + (wi & 7);
            colb = wi >> 3;
        } else { rowb = blockIdx.y; colb = blockIdx.x; }
    }
    const int row0 = rowb << 7, col0 = colb << 7;
    const int wave = tid >> 6, lane = tid & 63;
    const int q = lane >> 4, l16 = lane & 15;

    f32x4 acc[2][8];
#pragma unroll
    for (int mt = 0; mt < 2; ++mt)
#pragma unroll
        for (int nt = 0; nt < 8; ++nt)
            acc[mt][nt] = (f32x4){0.f, 0.f, 0.f, 0.f};

    const int bn = tid >> 1, bhf = (tid & 1) << 4;   // B/A copy: row, k-half

    const int nk = Kpad >> 5;
    for (int t = 0; t < nk; ++t) {
        const int k0 = t << 5;
        // ---- stage A
        if (Aph) {
            const long s = (long)(row0 + bn) * Kpad + k0 + bhf;
            *(int4*)&Ah[bn * LDK + bhf + 0] = *(const int4*)&Aph[s + 0];
            *(int4*)&Ah[bn * LDK + bhf + 8] = *(const int4*)&Aph[s + 8];
            *(int4*)&Al[bn * LDK + bhf + 0] = *(const int4*)&Apl[s + 0];
            *(int4*)&Al[bn * LDK + bhf + 8] = *(const int4*)&Apl[s + 8];
        } else {
#pragma unroll
            for (int s = 0; s < 4; ++s) {
                const int l  = (s << 8) + tid;
                const int m  = l >> 3;
                const int k4 = (l & 7) << 2;
                const float4 v = *(const float4*)&Afp[(long)(row0 + m) * Kpad + k0 + k4];
                const unsigned u0 = __float_as_uint(v.x), u1 = __float_as_uint(v.y);
                const unsigned u2 = __float_as_uint(v.z), u3 = __float_as_uint(v.w);
                const unsigned r0 = __float_as_uint(v.x - __uint_as_float(u0 & 0xFFFF0000u));
                const unsigned r1 = __float_as_uint(v.y - __uint_as_float(u1 & 0xFFFF0000u));
                const unsigned r2 = __float_as_uint(v.z - __uint_as_float(u2 & 0xFFFF0000u));
                const unsigned r3 = __float_as_uint(v.w - __uint_as_float(u3 & 0xFFFF0000u));
                *(int2*)&Ah[m * LDK + k4] = make_int2((int)pack_hi(u0, u1), (int)pack_hi(u2, u3));
                *(int2*)&Al[m * LDK + k4] = make_int2((int)pack_hi(r0, r1), (int)pack_hi(r2, r3));
            }
        }
        // ---- stage B: vector copies from pre-split planes
        {
            const long s = (long)(col0 + bn) * Kpad + k0 + bhf;
            *(int4*)&Bh[bn * LDK + bhf + 0] = *(const int4*)&Wth[s + 0];
            *(int4*)&Bh[bn * LDK + bhf + 8] = *(const int4*)&Wth[s + 8];
            *(int4*)&Bl[bn * LDK + bhf + 0] = *(const int4*)&Wtl[s + 0];
            *(int4*)&Bl[bn * LDK + bhf + 8] = *(const int4*)&Wtl[s + 8];
        }
        __syncthreads();
        // ---- MFMA
        bf16x8 ah[2], al[2];
#pragma unroll
        for (int mt = 0; mt < 2; ++mt) {
            const int mrow = (wave << 5) + (mt << 4) + l16;
            ah[mt] = *(const bf16x8*)&Ah[mrow * LDK + (q << 3)];
            al[mt] = *(const bf16x8*)&Al[mrow * LDK + (q << 3)];
        }
#pragma unroll
        for (int nt = 0; nt < 8; ++nt) {
            const int ncol2 = (nt << 4) + l16;
            const bf16x8 bh = *(const bf16x8*)&Bh[ncol2 * LDK + (q << 3)];
            const bf16x8 bl = *(const bf16x8*)&Bl[ncol2 * LDK + (q << 3)];
#pragma unroll
            for (int mt = 0; mt < 2; ++mt) {
                acc[mt][nt] = __builtin_amdgcn_mfma_f32_16x16x32_bf16(ah[mt], bh, acc[mt][nt], 0, 0, 0);
                acc[mt][nt] = __builtin_amdgcn_mfma_f32_16x16x32_bf16(ah[mt], bl, acc[mt][nt], 0, 0, 0);
                acc[mt][nt] = __builtin_amdgcn_mfma_f32_16x16x32_bf16(al[mt], bh, acc[mt][nt], 0, 0, 0);
            }
        }
        __syncthreads();
    }
    // ---- epilogue: C/D layout col=lane&15, row=quad*4+reg
#pragma unroll
    for (int mt = 0; mt < 2; ++mt)
#pragma unroll
        for (int nt = 0; nt < 8; ++nt) {
            const int col = col0 + (nt << 4) + l16;
            const float bs = bias[col];
#pragma unroll
            for (int rg = 0; rg < 4; ++rg) {
                const int row = row0 + (wave << 5) + (mt << 4) + (q << 2) + rg;
                float v = acc[mt][nt][rg] + bs;
                if (relu) v = fmaxf(v, 0.f);
                if (Cf) Cf[(long)row * N + col] = v;
                if (Cph) {
                    short h, l; split1(v, h, l);
                    Cph[(long)row * KpadOut + col] = h;
                    Cpl[(long)row * KpadOut + col] = l;
                }
            }
        }
}

// ---------------------------------------------------------------------------
// LayerNorm: fp32 in -> split planes out (256 features/row)
// ---------------------------------------------------------------------------
__global__ __launch_bounds__(256) void ln_kernel(const float* __restrict__ z,
                                                 const float* __restrict__ g,
                                                 const float* __restrict__ b,
                                                 short* __restrict__ hp,
                                                 short* __restrict__ lp)
{
    const int r = blockIdx.x, tid = threadIdx.x;
    float x = z[(long)r * 256 + tid];
    __shared__ float part[4];
    __shared__ float mu_s, den_s;
    float s = x;
#pragma unroll
    for (int off = 32; off; off >>= 1) s += __shfl_down(s, off);
    if ((tid & 63) == 0) part[tid >> 6] = s;
    __syncthreads();
    if (tid == 0) mu_s = (part[0] + part[1] + part[2] + part[3]) * (1.f / 256.f);
    __syncthreads();
    const float mu = mu_s;
    const float d = x - mu;
    float s2 = d * d;
#pragma unroll
    for (int off = 32; off; off >>= 1) s2 += __shfl_down(s2, off);
    if ((tid & 63) == 0) part[tid >> 6] = s2;
    __syncthreads();
    if (tid == 0)
        den_s = sqrtf((part[0] + part[1] + part[2] + part[3]) * (1.f / 256.f) + 1e-5f);
    __syncthreads();
    const float v = d / den_s * g[tid] + b[tid];
    short h, l; split1(v, h, l);
    hp[(long)r * 256 + tid] = h;
    lp[(long)r * 256 + tid] = l;
}

// ---------------------------------------------------------------------------
// imp = z2 @ iw3 + ib3 ; pert = (imp + noise)/max(exp(lt),0.1)
// ---------------------------------------------------------------------------
__global__ __launch_bounds__(256) void imp_kernel(const float* __restrict__ z2,
                                                  const float* __restrict__ iw3,
                                                  const float* __restrict__ ib3,
                                                  const float* __restrict__ noise,
                                                  const float* __restrict__ lt,
                                                  float* __restrict__ pert,
                                                  int base)
{
    const int r = blockIdx.x, tid = threadIdx.x;
    float v = z2[(long)r * 256 + tid] * iw3[tid];
    __shared__ float part[4];
#pragma unroll
    for (int off = 32; off; off >>= 1) v += __shfl_down(v, off);
    if ((tid & 63) == 0) part[tid >> 6] = v;
    __syncthreads();
    if (tid == 0) {
        const float imp  = part[0] + part[1] + part[2] + part[3] + ib3[0];
        const float temp = fmaxf(expf(lt[0]), 0.1f);
        pert[base + r] = (imp + noise[base + r]) / temp;
    }
}

// ---------------------------------------------------------------------------
// top-128 per event via 4-pass radix-select + exact ties + bitonic order.
// ---------------------------------------------------------------------------
__device__ __forceinline__ unsigned fmap(float f) {
    unsigned x = __float_as_uint(f);
    return (x & 0x80000000u) ? ~x : (x | 0x80000000u);
}

__global__ __launch_bounds__(256) void topk_kernel(const float* __restrict__ pert,
                                                   const float* __restrict__ coords,
                                                   float* __restrict__ centf)
{
    const int e = blockIdx.x, tid = threadIdx.x;
    const int base = e * PPE;
    __shared__ unsigned hist[256];
    __shared__ unsigned sh_prefix;
    __shared__ int sh_need;
    unsigned prefix = 0, known = 0;
    int need = MT;
    for (int shift = 24; shift >= 0; shift -= 8) {
        hist[tid] = 0;
        __syncthreads();
        for (int i = tid; i < PPE; i += 256) {
            const unsigned u = fmap(pert[base + i]);
            if ((u & known) == prefix) atomicAdd(&hist[(u >> shift) & 255u], 1u);
        }
        __syncthreads();
        if (tid == 0) {
            int cum = 0, b = 255;
            for (; b > 0; --b) { cum += (int)hist[b]; if (cum >= need) break; }
            if (cum < need) { cum += (int)hist[0]; b = 0; }
            sh_need   = need - (cum - (int)hist[b]);
            sh_prefix = prefix | ((unsigned)b << shift);
        }
        __syncthreads();
        need   = sh_need;
        prefix = sh_prefix;
        known |= (255u << shift);
        __syncthreads();
    }
    const unsigned T = prefix;
    const int need_eq = need;

    __shared__ unsigned selu[MT];
    __shared__ int      seli[MT];
    __shared__ int cgt, ceq;
    __shared__ int eqbuf[256];
    if (tid == 0) { cgt = 0; ceq = 0; }
    __syncthreads();
    for (int i = tid; i < PPE; i += 256) {
        const unsigned u = fmap(pert[base + i]);
        if (u > T)       { int p = atomicAdd(&cgt, 1); selu[p] = u; seli[p] = i; }
        else if (u == T) { int p = atomicAdd(&ceq, 1); if (p < 256) eqbuf[p] = i; }
    }
    __syncthreads();
    const int ngt = cgt;
    if (ceq <= 256) {
        if (tid >= ceq) eqbuf[tid] = 0x7FFFFFFF;
        __syncthreads();
        for (int k = 2; k <= 256; k <<= 1)
            for (int j = k >> 1; j > 0; j >>= 1) {
                const int l = tid ^ j;
                if (l > tid) {
                    const int a = eqbuf[tid], b = eqbuf[l];
                    const bool up = ((tid & k) == 0);
                    if (up ? (a > b) : (a < b)) { eqbuf[tid] = b; eqbuf[l] = a; }
                }
                __syncthreads();
            }
        if (tid < need_eq) { selu[ngt + tid] = T; seli[ngt + tid] = eqbuf[tid]; }
    } else if (tid == 0) {
        int cur = -1;
        for (int qq = 0; qq < need_eq; ++qq) {
            int best = 0x7FFFFFFF;
            for (int i = 0; i < PPE; ++i)
                if (i > cur && fmap(pert[base + i]) == T && i < best) best = i;
            selu[ngt + qq] = T; seli[ngt + qq] = best; cur = best;
        }
    }
    __syncthreads();
    __shared__ unsigned long long key[MT];
    if (tid < MT)
        key[tid] = ((unsigned long long)selu[tid] << 32) | (unsigned)(~seli[tid]);
    __syncthreads();
    for (int k = 2; k <= MT; k <<= 1)
        for (int j = k >> 1; j > 0; j >>= 1) {
            if (tid < MT) {
                const int l = tid ^ j;
                if (l > tid) {
                    const unsigned long long a = key[tid], b = key[l];
                    const bool up = ((tid & k) == 0);
                    if (up ? (a < b) : (a > b)) { key[tid] = b; key[l] = a; }
                }
            }
            __syncthreads();
        }
    if (tid < MT) {
        const int idx = (int)(~(unsigned)(key[tid] & 0xFFFFFFFFu));
        const long cb = (long)(base + idx) * 5;
        centf[(long)(e * MT + tid) * 4 + 0] = coords[cb + 1];
        centf[(long)(e * MT + tid) * 4 + 1] = coords[cb + 2];
        centf[(long)(e * MT + tid) * 4 + 2] = coords[cb + 3];
        centf[(long)(e * MT + tid) * 4 + 3] = coords[cb + 4];
    }
}

// ---------------------------------------------------------------------------
// per (event,centroid): 16-NN (smallest d2, ties -> lower index).
// ---------------------------------------------------------------------------
__global__ __launch_bounds__(256) void knn_kernel(const float* __restrict__ coords,
                                                  const float* __restrict__ centf,
                                                  int* __restrict__ knn_idx)
{
    const int blk = blockIdx.x;
    const int e = blk >> 7;
    const int tid = threadIdx.x;
    const int base = e * PPE;
    const float c0 = centf[(long)blk * 4 + 0];
    const float c1 = centf[(long)blk * 4 + 1];
    const float c2 = centf[(long)blk * 4 + 2];
    const float c3 = centf[(long)blk * 4 + 3];
    float ld[KNN]; int li[KNN];
#pragma unroll
    for (int i = 0; i < KNN; ++i) { ld[i] = 3.4e38f; li[i] = 0x7FFFFFFF; }
    for (int p = tid; p < PPE; p += 256) {
        const long cb = (long)(base + p) * 5;
        const float x0 = coords[cb + 1];
        const float x1 = coords[cb + 2];
        const float x2 = coords[cb + 3];
        const float x3 = coords[cb + 4];
        const float q0 = __fmul_rn(c0 - x0, c0 - x0);
        const float q1 = __fmul_rn(c1 - x1, c1 - x1);
        const float q2 = __fmul_rn(c2 - x2, c2 - x2);
        const float q3 = __fmul_rn(c3 - x3, c3 - x3);
        const float d  = __fadd_rn(__fadd_rn(__fadd_rn(q0, q1), q2), q3);
        if (d < ld[KNN - 1] || (d == ld[KNN - 1] && p < li[KNN - 1])) {
            int j = KNN - 1;
            while (j > 0 && (d < ld[j - 1] || (d == ld[j - 1] && p < li[j - 1]))) {
                ld[j] = ld[j - 1]; li[j] = li[j - 1]; --j;
            }
            ld[j] = d; li[j] = p;
        }
    }
    __shared__ float hv[256];
    __shared__ int   hi2[256];
    __shared__ int   ho[256];
    int ptr = 0;
    for (int r = 0; r < KNN; ++r) {
        hv[tid]  = (ptr < KNN) ? ld[ptr] : 3.4e38f;
        hi2[tid] = (ptr < KNN) ? li[ptr] : 0x7FFFFFFF;
        ho[tid]  = tid;
        __syncthreads();
        for (int s = 128; s > 0; s >>= 1) {
            if (tid < s) {
                const float v2 = hv[tid + s]; const int i2 = hi2[tid + s];
                if (v2 < hv[tid] || (v2 == hv[tid] && i2 < hi2[tid])) {
                    hv[tid] = v2; hi2[tid] = i2; ho[tid] = ho[tid + s];
                }
            }
            __syncthreads();
        }
        if (tid == ho[0]) ptr++;
        if (tid == 0) {
            int ix = hi2[0];
            ix = (ix < 0) ? 0 : ((ix >= PPE) ? (PPE - 1) : ix);
            knn_idx[blk * KNN + r] = base + ix;
        }
        __syncthreads();
    }
}

// ---------------------------------------------------------------------------
// pooled[blk][t] = max over 16 recomputed-pf neighbor rows
// ---------------------------------------------------------------------------
__global__ __launch_bounds__(256) void pool_kernel(const float* __restrict__ pf_nbr,
                                                   float* __restrict__ pooled)
{
    const int blk = blockIdx.x, tid = threadIdx.x;
    for (int t = tid; t < TOKD; t += 256) {
        float mx = -3.4e38f;
#pragma unroll
        for (int j = 0; j < KNN; ++j)
            mx = fmaxf(mx, pf_nbr[(long)(blk * KNN + j) * TOKD + t]);
        pooled[(long)blk * TOKD + t] = mx;
    }
}

// ---------------------------------------------------------------------------
// batched emit: block e; stable rank by cent[:,3] asc; fp32 out.
// ---------------------------------------------------------------------------
__global__ __launch_bounds__(256) void emit_kernel(const float* __restrict__ centf,
                                                   const float* __restrict__ tokf,
                                                   float* __restrict__ out,
                                                   long out_size)
{
    const int e = blockIdx.x, tid = threadIdx.x;
    const float* tokf_e = tokf + (size_t)e * MT * TOKD;
    __shared__ float tv[MT];
    __shared__ int   rk[MT];
    if (tid < MT) tv[tid] = centf[(long)(e * MT + tid) * 4 + 3];
    __syncthreads();
    if (tid < MT) {
        const float t = tv[tid]; int r = 0;
        for (int j = 0; j < MT; ++j)
            r += (tv[j] < t || (tv[j] == t && j < tid)) ? 1 : 0;
        rk[tid] = r;
    }
    __syncthreads();
    const long cent_off = (long)BATCH * MT * TOKD;
    const long mask_off = cent_off + (long)BATCH * MT * 4;
    for (int idx = tid; idx < MT * TOKD; idx += 256) {
        const int i = idx / TOKD, t = idx % TOKD;
        const long g = ((long)e * MT + rk[i]) * TOKD + t;
        if (g < out_size) out[g] = tokf_e[(long)i * TOKD + t];
    }
    for (int idx = tid; idx < MT * 4; idx += 256) {
        const int i = idx >> 2, d = idx & 3;
        const long g = cent_off + ((long)e * MT + rk[i]) * 4 + d;
        if (g < out_size) out[g] = centf[((long)e * MT + i) * 4 + d];
    }
    for (int idx = tid; idx < MT; idx += 256) {
        const long g = mask_off + (long)e * MT + idx;
        if (g < out_size) out[g] = 1.0f;
    }
}

// ---------------------------------------------------------------------------
extern "C" void kernel_launch(void* const* d_in, const int* in_sizes, int n_in,
                              void* d_out, int out_size, void* d_ws, size_t ws_size,
                              hipStream_t stream)
{
    const float* coords = (const float*)d_in[0];
    const float* feats  = (const float*)d_in[1];
    const float* lt     = (const float*)d_in[2];
    const float* w1  = (const float*)d_in[3];  const float* b1  = (const float*)d_in[4];
    const float* w2  = (const float*)d_in[5];  const float* b2  = (const float*)d_in[6];
    const float* w3  = (const float*)d_in[7];  const float* b3  = (const float*)d_in[8];
    const float* w4  = (const float*)d_in[9];  const float* b4  = (const float*)d_in[10];
    const float* iw1 = (const float*)d_in[11]; const float* ib1 = (const float*)d_in[12];
    const float* lng = (const float*)d_in[13]; const float* lnb = (const float*)d_in[14];
    const float* iw2 = (const float*)d_in[15]; const float* ib2 = (const float*)d_in[16];
    const float* iw3 = (const float*)d_in[17]; const float* ib3 = (const float*)d_in[18];
    const float* nw1 = (const float*)d_in[19]; const float* nb1 = (const float*)d_in[20];
    const float* nw2 = (const float*)d_in[21]; const float* nb2 = (const float*)d_in[22];
    const float* noise = (const float*)d_in[23];

    // ---- ws layout ----
    const size_t FIXED_FL = (size_t)NPT + 4096 + 16384 + (size_t)1024 * TOKD;
    const size_t s_w2 = 512 * 256,  s_w3 = 768 * 512,  s_w4 = 768 * 768;
    const size_t s_i1 = 256 * 800,  s_i2 = 256 * 256;
    const size_t s_n1 = 768 * 768,  s_n2 = 768 * 768;
    const size_t WTOT = 2 * (s_w2 + s_w3 + s_w4 + s_i1 + s_i2 + s_n1 + s_n2);
    const size_t BASE_BYTES = FIXED_FL * 4 + WTOT * 2;
    // per-row bytes: P1 (2x768 sh) 3072 + P2 (2x800 sh) 3200 + F1 3072 + F2 1024
    const size_t PERROW = 10368;
    int ch = 128;
    while (ch < NPT && BASE_BYTES + (size_t)(ch * 2) * PERROW <= ws_size) ch <<= 1;

    float* pert   = (float*)d_ws;                       // NPT
    float* centf  = pert + NPT;                         // 1024*4
    int*   knn    = (int*)(centf + 4096);               // 16384 ints
    float* pooled = (float*)(knn + 16384);              // 1024*768
    short* wsp    = (short*)(pooled + (size_t)1024 * TOKD);
    short* w2h = wsp;            short* w2l = w2h + s_w2;
    short* w3h = w2l + s_w2;     short* w3l = w3h + s_w3;
    short* w4h = w3l + s_w3;     short* w4l = w4h + s_w4;
    short* i1h = w4l + s_w4;     short* i1l = i1h + s_i1;
    short* i2h = i1l + s_i1;     short* i2l = i2h + s_i2;
    short* n1h = i2l + s_i2;     short* n1l = n1h + s_n1;
    short* n2h = n1l + s_n1;     short* n2l = n2h + s_n2;
    short* P1h = n2l + s_n2;     short* P1l = P1h + (size_t)ch * 768;
    short* P2h = P1l + (size_t)ch * 768;
    short* P2l = P2h + (size_t)ch * 800;
    float* F1  = (float*)(P2l + (size_t)ch * 800);      // ch*768 fp32
    float* F2  = F1 + (size_t)ch * 768;                 // ch*256 fp32

    // ---- pre-convert weights (once per launch; deterministic) ----
    wsplit_kernel<<<dim3(512), dim3(256), 0, stream>>>(w2, 256, 512, 256, w2h, w2l);
    wsplit_kernel<<<dim3(768), dim3(256), 0, stream>>>(w3, 512, 768, 512, w3h, w3l);
    wsplit_kernel<<<dim3(768), dim3(256), 0, stream>>>(w4, 768, 768, 768, w4h, w4l);
    wsplit_kernel<<<dim3(256), dim3(256), 0, stream>>>(iw1, 772, 256, 800, i1h, i1l);
    wsplit_kernel<<<dim3(256), dim3(256), 0, stream>>>(iw2, 256, 256, 256, i2h, i2l);
    wsplit_kernel<<<dim3(768), dim3(256), 0, stream>>>(nw1, 768, 768, 768, n1h, n1l);
    wsplit_kernel<<<dim3(768), dim3(256), 0, stream>>>(nw2, 768, 768, 768, n2h, n2l);

    // ---- chunked MLP: features -> pert (selection chain) ----
    for (int ck = 0; ck < NPT / ch; ++ck) {
        const int base = ck * ch;
        l1_kernel<<<dim3(ch), dim3(256), 0, stream>>>(feats, w1, b1, P1h, P1l, base, nullptr);
        gemm_mf<<<dim3(512 / 128, ch / 128), dim3(256), 0, stream>>>(
            P1h, P1l, nullptr, 256, w2h, w2l, b2, P2h, P2l, 512, nullptr, 512, 1);
        gemm_mf<<<dim3(768 / 128, ch / 128), dim3(256), 0, stream>>>(
            P2h, P2l, nullptr, 512, w3h, w3l, b3, P1h, P1l, 768, nullptr, 768, 1);
        gemm_mf<<<dim3(768 / 128, ch / 128), dim3(256), 0, stream>>>(
            P1h, P1l, nullptr, 768, w4h, w4l, b4, P2h, P2l, 800, nullptr, 768, 0);
        a2fill_kernel<<<dim3((ch * 32 + 255) / 256), dim3(256), 0, stream>>>(
            coords, base, ch, P2h, P2l);
        gemm_mf<<<dim3(256 / 128, ch / 128), dim3(256), 0, stream>>>(
            P2h, P2l, nullptr, 800, i1h, i1l, ib1, nullptr, nullptr, 0, F2, 256, 1);
        ln_kernel<<<dim3(ch), dim3(256), 0, stream>>>(F2, lng, lnb, P1h, P1l);
        gemm_mf<<<dim3(256 / 128, ch / 128), dim3(256), 0, stream>>>(
            P1h, P1l, nullptr, 256, i2h, i2l, ib2, nullptr, nullptr, 0, F1, 256, 1);
        imp_kernel<<<dim3(ch), dim3(256), 0, stream>>>(F1, iw3, ib3, noise, lt, pert, base);
    }

    // ---- selection + KNN ----
    topk_kernel<<<dim3(BATCH), dim3(256), 0, stream>>>(pert, coords, centf);
    knn_kernel<<<dim3(BATCH * MT), dim3(256), 0, stream>>>(coords, centf, knn);

    // ---- recompute pf for the 16384 gathered neighbor rows (chunked), pool --
    const int NBR  = BATCH * MT * KNN;   // 16384
    const int rcch = (ch < NBR) ? ch : NBR;
    for (int rc = 0; rc < NBR / rcch; ++rc) {
        l1_kernel<<<dim3(rcch), dim3(256), 0, stream>>>(feats, w1, b1, P1h, P1l, 0, knn + (size_t)rc * rcch);
        gemm_mf<<<dim3(512 / 128, rcch / 128), dim3(256), 0, stream>>>(
            P1h, P1l, nullptr, 256, w2h, w2l, b2, P2h, P2l, 512, nullptr, 512, 1);
        gemm_mf<<<dim3(768 / 128, rcch / 128), dim3(256), 0, stream>>>(
            P2h, P2l, nullptr, 512, w3h, w3l, b3, P1h, P1l, 768, nullptr, 768, 1);
        gemm_mf<<<dim3(768 / 128, rcch / 128), dim3(256), 0, stream>>>(
            P1h, P1l, nullptr, 768, w4h, w4l, b4, nullptr, nullptr, 0, F1, 768, 0);
        pool_kernel<<<dim3(rcch / KNN), dim3(256), 0, stream>>>(
            F1, pooled + (size_t)rc * (rcch / KNN) * TOKD);
    }

    // ---- token MLP (1024x768, fp32-A mode) + emit ----
    if (ch >= 1024) {
        float* t1   = (float*)P1h;                 // overlay plane region
        float* tokf = t1 + (size_t)1024 * TOKD;
        gemm_mf<<<dim3(768 / 128, 1024 / 128), dim3(256), 0, stream>>>(
            nullptr, nullptr, pooled, 768, n1h, n1l, nb1, nullptr, nullptr, 0, t1, 768, 1);
        gemm_mf<<<dim3(768 / 128, 1024 / 128), dim3(256), 0, stream>>>(
            nullptr, nullptr, t1, 768, n2h, n2l, nb2, nullptr, nullptr, 0, tokf, 768, 0);
        emit_kernel<<<dim3(BATCH), dim3(256), 0, stream>>>(
            centf, tokf, (float*)d_out, (long)out_size);
    } else {
        float* t1   = (float*)P1h;                 // 128*768 each, fits ch>=128
        float* tokf = t1 + (size_t)MT * TOKD;
        for (int e = 0; e < BATCH; ++e) {
            gemm_mf<<<dim3(768 / 128, 1), dim3(256), 0, stream>>>(
                nullptr, nullptr, pooled + (size_t)e * MT * TOKD, 768,
                n1h, n1l, nb1, nullptr, nullptr, 0, t1, 768, 1);
            gemm_mf<<<dim3(768 / 128, 1), dim3(256), 0, stream>>>(
                nullptr, nullptr, t1, 768, n2h, n2l, nb2, nullptr, nullptr, 0, tokf, 768, 0);
            emit_kernel<<<dim3(1), dim3(256), 0, stream>>>(
                centf, tokf, (float*)d_out, (long)out_size);
        }
    }
}

// Round 12
// 2495.887 us; speedup vs baseline: 3.1779x; 1.0469x over previous
//
#include <hip/hip_runtime.h>
#include <hip/hip_bf16.h>

// GumbelSoftmaxTokenizer: B=8, P=16384, FEAT=6, TOK=768, MT=128, K=16, IH=256
// All inputs float32; output buffer float32 (tokens, cents, masks concat).
#define NPT   131072      // B*P
#define BATCH 8
#define PPE   16384
#define MT    128
#define KNN   16
#define TOKD  768

typedef short bf16x8 __attribute__((ext_vector_type(8)));
typedef float f32x4  __attribute__((ext_vector_type(4)));

// global->LDS direct copy, 16B per lane (gfx950). LDS dest is wave-uniform
// base; HW scatters lane l to base + l*16B.
#define GL16(g, l) __builtin_amdgcn_global_load_lds(                         \
    (const __attribute__((address_space(1))) void*)(g),                      \
    (__attribute__((address_space(3))) void*)(l), 16, 0, 0)

__device__ __forceinline__ unsigned pack_hi(unsigned u0, unsigned u1) {
    return (u0 >> 16) | (u1 & 0xFFFF0000u);   // bf16 pair (e0,e1), truncated
}
__device__ __forceinline__ void split1(float x, short& h, short& l) {
    const unsigned u = __float_as_uint(x);
    h = (short)(u >> 16);
    const float r = x - __uint_as_float(u & 0xFFFF0000u);
    l = (short)(__float_as_uint(r) >> 16);
}

// ---------------------------------------------------------------------------
// prep: c4f[i] = coords[i,1:5] as packed float4 (exact copies)
// ---------------------------------------------------------------------------
__global__ __launch_bounds__(256) void prep_kernel(const float* __restrict__ coords,
                                                   float4* __restrict__ c4f)
{
    const int i = blockIdx.x * 256 + threadIdx.x;
    if (i < NPT) {
        const long b = (long)i * 5;
        c4f[i] = make_float4(coords[b + 1], coords[b + 2], coords[b + 3], coords[b + 4]);
    }
}

// ---------------------------------------------------------------------------
// Weight pre-convert: W(KxN f32) -> hi/lo [N][Kpad] bf16 (transposed, padded)
// ---------------------------------------------------------------------------
__global__ __launch_bounds__(256) void wsplit_kernel(const float* __restrict__ W,
                                                     int K, int N, int Kpad,
                                                     short* __restrict__ hi,
                                                     short* __restrict__ lo)
{
    const int n = blockIdx.x;
    for (int k = threadIdx.x; k < Kpad; k += 256) {
        short h = 0, l = 0;
        if (k < K) split1(W[(long)k * N + n], h, l);
        hi[(long)n * Kpad + k] = h;
        lo[(long)n * Kpad + k] = l;
    }
}

// ---------------------------------------------------------------------------
// L1: h1 = relu(features @ w1 + b1) -> split planes [r][256]
// ---------------------------------------------------------------------------
__global__ __launch_bounds__(256) void l1_kernel(const float* __restrict__ f,
                                                 const float* __restrict__ w1,
                                                 const float* __restrict__ b1,
                                                 short* __restrict__ hp,
                                                 short* __restrict__ lp,
                                                 int base,
                                                 const int* __restrict__ gather)
{
    const int r = blockIdx.x, n = threadIdx.x;
    int row = gather ? gather[r] : (base + r);
    row = (row < 0) ? 0 : ((row >= NPT) ? (NPT - 1) : row);
    __shared__ float fs[6];
    if (threadIdx.x < 6) fs[threadIdx.x] = f[(long)row * 6 + threadIdx.x];
    __syncthreads();
    float acc = b1[n];
#pragma unroll
    for (int k = 0; k < 6; ++k) acc += fs[k] * w1[k * 256 + n];
    acc = fmaxf(acc, 0.f);
    short h, l; split1(acc, h, l);
    hp[(long)r * 256 + n] = h;
    lp[(long)r * 256 + n] = l;
}

// ---------------------------------------------------------------------------
// a2fill: plane cols 768..799 of the pf planes (Kpad=800)
// ---------------------------------------------------------------------------
__global__ __launch_bounds__(256) void a2fill_kernel(const float* __restrict__ coords,
                                                     int base, int ch,
                                                     short* __restrict__ hp,
                                                     short* __restrict__ lp)
{
    const int idx = blockIdx.x * 256 + threadIdx.x;
    if (idx >= ch * 32) return;
    const int r = idx >> 5, c = idx & 31;
    short h = 0, l = 0;
    if (c < 4) split1(coords[(long)(base + r) * 5 + 1 + c], h, l);
    hp[(long)r * 800 + 768 + c] = h;
    lp[(long)r * 800 + 768 + c] = l;
}

// ---------------------------------------------------------------------------
// Split-bf16 MFMA GEMM (3-product, hh+hl+lh): C = [relu](A @ W + bias).
// A: split planes [M][Kpad] (Aph/Apl, staged via global_load_lds) OR fp32
// [M][Kpad] (Afp, converted at stage). B: pre-split planes [N][Kpad],
// global_load_lds. LDS layout unpadded [row][32] (GL16 constraint).
// Block 128x128, BK=32, 4 waves x (32x128). XCD-congruent swizzle.
// M,N multiples of 128; Kpad multiple of 32.
// ---------------------------------------------------------------------------
__global__ __launch_bounds__(256) void gemm_mf(
    const short* __restrict__ Aph, const short* __restrict__ Apl,
    const float* __restrict__ Afp, int Kpad,
    const short* __restrict__ Wth, const short* __restrict__ Wtl,
    const float* __restrict__ bias,
    short* __restrict__ Cph, short* __restrict__ Cpl, int KpadOut,
    float* __restrict__ Cf,
    int N, int relu)
{
    __shared__ short Ah[128 * 32];
    __shared__ short Al[128 * 32];
    __shared__ short Bh[128 * 32];
    __shared__ short Bl[128 * 32];
    const int tid = threadIdx.x;
    // ---- swizzle: col-blocks of a row-block stay on one XCD, adjacent in time
    int rowb, colb;
    {
        const int ncol = gridDim.x, nrow = gridDim.y;
        if ((nrow & 7) == 0) {
            const int id  = blockIdx.y * ncol + blockIdx.x;
            const int sgs = ncol << 3;
            const int sg = id / sgs, wi = id % sgs;
            rowb = (sg << 3) + (wi & 7);
            colb = wi >> 3;
        } else { rowb = blockIdx.y; colb = blockIdx.x; }
    }
    const int row0 = rowb << 7, col0 = colb << 7;
    const int wave = tid >> 6, lane = tid & 63;
    const int q = lane >> 4, l16 = lane & 15;
    const int l2 = lane >> 2;            // GL16 row-within-16 group
    const int ks = (lane & 3) << 3;      // GL16 k sub-offset (shorts)

    f32x4 acc[2][8];
#pragma unroll
    for (int mt = 0; mt < 2; ++mt)
#pragma unroll
        for (int nt = 0; nt < 8; ++nt)
            acc[mt][nt] = (f32x4){0.f, 0.f, 0.f, 0.f};

    const int nk = Kpad >> 5;
    for (int t = 0; t < nk; ++t) {
        const int k0 = t << 5;
        // ---- stage B: direct global->LDS (2x16 rows per wave per plane)
#pragma unroll
        for (int i = 0; i < 2; ++i) {
            const int mb = (wave << 5) + (i << 4);
            const long gb = (long)(col0 + mb + l2) * Kpad + k0 + ks;
            GL16(&Wth[gb], &Bh[mb * 32]);
            GL16(&Wtl[gb], &Bl[mb * 32]);
        }
        // ---- stage A
        if (Aph) {
#pragma unroll
            for (int i = 0; i < 2; ++i) {
                const int mb = (wave << 5) + (i << 4);
                const long ga = (long)(row0 + mb + l2) * Kpad + k0 + ks;
                GL16(&Aph[ga], &Ah[mb * 32]);
                GL16(&Apl[ga], &Al[mb * 32]);
            }
        } else {
#pragma unroll
            for (int s = 0; s < 4; ++s) {
                const int l  = (s << 8) + tid;
                const int m  = l >> 3;
                const int k4 = (l & 7) << 2;
                const float4 v = *(const float4*)&Afp[(long)(row0 + m) * Kpad + k0 + k4];
                const unsigned u0 = __float_as_uint(v.x), u1 = __float_as_uint(v.y);
                const unsigned u2 = __float_as_uint(v.z), u3 = __float_as_uint(v.w);
                const unsigned r0 = __float_as_uint(v.x - __uint_as_float(u0 & 0xFFFF0000u));
                const unsigned r1 = __float_as_uint(v.y - __uint_as_float(u1 & 0xFFFF0000u));
                const unsigned r2 = __float_as_uint(v.z - __uint_as_float(u2 & 0xFFFF0000u));
                const unsigned r3 = __float_as_uint(v.w - __uint_as_float(u3 & 0xFFFF0000u));
                *(int2*)&Ah[m * 32 + k4] = make_int2((int)pack_hi(u0, u1), (int)pack_hi(u2, u3));
                *(int2*)&Al[m * 32 + k4] = make_int2((int)pack_hi(r0, r1), (int)pack_hi(r2, r3));
            }
        }
        __syncthreads();   // drains vmcnt (global_load_lds) + lgkm before use
        // ---- MFMA
        bf16x8 ah[2], al[2];
#pragma unroll
        for (int mt = 0; mt < 2; ++mt) {
            const int mrow = (wave << 5) + (mt << 4) + l16;
            ah[mt] = *(const bf16x8*)&Ah[mrow * 32 + (q << 3)];
            al[mt] = *(const bf16x8*)&Al[mrow * 32 + (q << 3)];
        }
#pragma unroll
        for (int nt = 0; nt < 8; ++nt) {
            const int ncol2 = (nt << 4) + l16;
            const bf16x8 bh = *(const bf16x8*)&Bh[ncol2 * 32 + (q << 3)];
            const bf16x8 bl = *(const bf16x8*)&Bl[ncol2 * 32 + (q << 3)];
#pragma unroll
            for (int mt = 0; mt < 2; ++mt) {
                acc[mt][nt] = __builtin_amdgcn_mfma_f32_16x16x32_bf16(ah[mt], bh, acc[mt][nt], 0, 0, 0);
                acc[mt][nt] = __builtin_amdgcn_mfma_f32_16x16x32_bf16(ah[mt], bl, acc[mt][nt], 0, 0, 0);
                acc[mt][nt] = __builtin_amdgcn_mfma_f32_16x16x32_bf16(al[mt], bh, acc[mt][nt], 0, 0, 0);
            }
        }
        __syncthreads();
    }
    // ---- epilogue: C/D layout col=lane&15, row=quad*4+reg
#pragma unroll
    for (int mt = 0; mt < 2; ++mt)
#pragma unroll
        for (int nt = 0; nt < 8; ++nt) {
            const int col = col0 + (nt << 4) + l16;
            const float bs = bias[col];
#pragma unroll
            for (int rg = 0; rg < 4; ++rg) {
                const int row = row0 + (wave << 5) + (mt << 4) + (q << 2) + rg;
                float v = acc[mt][nt][rg] + bs;
                if (relu) v = fmaxf(v, 0.f);
                if (Cf) Cf[(long)row * N + col] = v;
                if (Cph) {
                    short h, l; split1(v, h, l);
                    Cph[(long)row * KpadOut + col] = h;
                    Cpl[(long)row * KpadOut + col] = l;
                }
            }
        }
}

// ---------------------------------------------------------------------------
// LayerNorm: fp32 in -> split planes out (256 features/row)
// ---------------------------------------------------------------------------
__global__ __launch_bounds__(256) void ln_kernel(const float* __restrict__ z,
                                                 const float* __restrict__ g,
                                                 const float* __restrict__ b,
                                                 short* __restrict__ hp,
                                                 short* __restrict__ lp)
{
    const int r = blockIdx.x, tid = threadIdx.x;
    float x = z[(long)r * 256 + tid];
    __shared__ float part[4];
    __shared__ float mu_s, den_s;
    float s = x;
#pragma unroll
    for (int off = 32; off; off >>= 1) s += __shfl_down(s, off);
    if ((tid & 63) == 0) part[tid >> 6] = s;
    __syncthreads();
    if (tid == 0) mu_s = (part[0] + part[1] + part[2] + part[3]) * (1.f / 256.f);
    __syncthreads();
    const float mu = mu_s;
    const float d = x - mu;
    float s2 = d * d;
#pragma unroll
    for (int off = 32; off; off >>= 1) s2 += __shfl_down(s2, off);
    if ((tid & 63) == 0) part[tid >> 6] = s2;
    __syncthreads();
    if (tid == 0)
        den_s = sqrtf((part[0] + part[1] + part[2] + part[3]) * (1.f / 256.f) + 1e-5f);
    __syncthreads();
    const float v = d / den_s * g[tid] + b[tid];
    short h, l; split1(v, h, l);
    hp[(long)r * 256 + tid] = h;
    lp[(long)r * 256 + tid] = l;
}

// ---------------------------------------------------------------------------
// imp = z2 @ iw3 + ib3 ; pert = (imp + noise)/max(exp(lt),0.1)
// ---------------------------------------------------------------------------
__global__ __launch_bounds__(256) void imp_kernel(const float* __restrict__ z2,
                                                  const float* __restrict__ iw3,
                                                  const float* __restrict__ ib3,
                                                  const float* __restrict__ noise,
                                                  const float* __restrict__ lt,
                                                  float* __restrict__ pert,
                                                  int base)
{
    const int r = blockIdx.x, tid = threadIdx.x;
    float v = z2[(long)r * 256 + tid] * iw3[tid];
    __shared__ float part[4];
#pragma unroll
    for (int off = 32; off; off >>= 1) v += __shfl_down(v, off);
    if ((tid & 63) == 0) part[tid >> 6] = v;
    __syncthreads();
    if (tid == 0) {
        const float imp  = part[0] + part[1] + part[2] + part[3] + ib3[0];
        const float temp = fmaxf(expf(lt[0]), 0.1f);
        pert[base + r] = (imp + noise[base + r]) / temp;
    }
}

// ---------------------------------------------------------------------------
// top-128 per event via 4-pass radix-select + exact ties + bitonic order.
// ---------------------------------------------------------------------------
__device__ __forceinline__ unsigned fmap(float f) {
    unsigned x = __float_as_uint(f);
    return (x & 0x80000000u) ? ~x : (x | 0x80000000u);
}

__global__ __launch_bounds__(256) void topk_kernel(const float* __restrict__ pert,
                                                   const float4* __restrict__ c4f,
                                                   float* __restrict__ centf)
{
    const int e = blockIdx.x, tid = threadIdx.x;
    const int base = e * PPE;
    __shared__ unsigned hist[256];
    __shared__ unsigned sh_prefix;
    __shared__ int sh_need;
    unsigned prefix = 0, known = 0;
    int need = MT;
    for (int shift = 24; shift >= 0; shift -= 8) {
        hist[tid] = 0;
        __syncthreads();
        for (int i = tid; i < PPE; i += 256) {
            const unsigned u = fmap(pert[base + i]);
            if ((u & known) == prefix) atomicAdd(&hist[(u >> shift) & 255u], 1u);
        }
        __syncthreads();
        if (tid == 0) {
            int cum = 0, b = 255;
            for (; b > 0; --b) { cum += (int)hist[b]; if (cum >= need) break; }
            if (cum < need) { cum += (int)hist[0]; b = 0; }
            sh_need   = need - (cum - (int)hist[b]);
            sh_prefix = prefix | ((unsigned)b << shift);
        }
        __syncthreads();
        need   = sh_need;
        prefix = sh_prefix;
        known |= (255u << shift);
        __syncthreads();
    }
    const unsigned T = prefix;
    const int need_eq = need;

    __shared__ unsigned selu[MT];
    __shared__ int      seli[MT];
    __shared__ int cgt, ceq;
    __shared__ int eqbuf[256];
    if (tid == 0) { cgt = 0; ceq = 0; }
    __syncthreads();
    for (int i = tid; i < PPE; i += 256) {
        const unsigned u = fmap(pert[base + i]);
        if (u > T)       { int p = atomicAdd(&cgt, 1); selu[p] = u; seli[p] = i; }
        else if (u == T) { int p = atomicAdd(&ceq, 1); if (p < 256) eqbuf[p] = i; }
    }
    __syncthreads();
    const int ngt = cgt;
    if (ceq <= 256) {
        if (tid >= ceq) eqbuf[tid] = 0x7FFFFFFF;
        __syncthreads();
        for (int k = 2; k <= 256; k <<= 1)
            for (int j = k >> 1; j > 0; j >>= 1) {
                const int l = tid ^ j;
                if (l > tid) {
                    const int a = eqbuf[tid], b = eqbuf[l];
                    const bool up = ((tid & k) == 0);
                    if (up ? (a > b) : (a < b)) { eqbuf[tid] = b; eqbuf[l] = a; }
                }
                __syncthreads();
            }
        if (tid < need_eq) { selu[ngt + tid] = T; seli[ngt + tid] = eqbuf[tid]; }
    } else if (tid == 0) {
        int cur = -1;
        for (int qq = 0; qq < need_eq; ++qq) {
            int best = 0x7FFFFFFF;
            for (int i = 0; i < PPE; ++i)
                if (i > cur && fmap(pert[base + i]) == T && i < best) best = i;
            selu[ngt + qq] = T; seli[ngt + qq] = best; cur = best;
        }
    }
    __syncthreads();
    __shared__ unsigned long long key[MT];
    if (tid < MT)
        key[tid] = ((unsigned long long)selu[tid] << 32) | (unsigned)(~seli[tid]);
    __syncthreads();
    for (int k = 2; k <= MT; k <<= 1)
        for (int j = k >> 1; j > 0; j >>= 1) {
            if (tid < MT) {
                const int l = tid ^ j;
                if (l > tid) {
                    const unsigned long long a = key[tid], b = key[l];
                    const bool up = ((tid & k) == 0);
                    if (up ? (a < b) : (a > b)) { key[tid] = b; key[l] = a; }
                }
            }
            __syncthreads();
        }
    if (tid < MT) {
        const int idx = (int)(~(unsigned)(key[tid] & 0xFFFFFFFFu));
        *(float4*)&centf[(long)(e * MT + tid) * 4] = c4f[base + idx];
    }
}

// ---------------------------------------------------------------------------
// per (event,centroid): 16-NN (smallest d2, ties -> lower index), float4 reads
// ---------------------------------------------------------------------------
__global__ __launch_bounds__(256) void knn_kernel(const float4* __restrict__ c4f,
                                                  const float* __restrict__ centf,
                                                  int* __restrict__ knn_idx)
{
    const int blk = blockIdx.x;
    const int e = blk >> 7;
    const int tid = threadIdx.x;
    const int base = e * PPE;
    const float c0 = centf[(long)blk * 4 + 0];
    const float c1 = centf[(long)blk * 4 + 1];
    const float c2 = centf[(long)blk * 4 + 2];
    const float c3 = centf[(long)blk * 4 + 3];
    float ld[KNN]; int li[KNN];
#pragma unroll
    for (int i = 0; i < KNN; ++i) { ld[i] = 3.4e38f; li[i] = 0x7FFFFFFF; }
    for (int p = tid; p < PPE; p += 256) {
        const float4 x = c4f[base + p];
        const float q0 = __fmul_rn(c0 - x.x, c0 - x.x);
        const float q1 = __fmul_rn(c1 - x.y, c1 - x.y);
        const float q2 = __fmul_rn(c2 - x.z, c2 - x.z);
        const float q3 = __fmul_rn(c3 - x.w, c3 - x.w);
        const float d  = __fadd_rn(__fadd_rn(__fadd_rn(q0, q1), q2), q3);
        if (d < ld[KNN - 1] || (d == ld[KNN - 1] && p < li[KNN - 1])) {
            int j = KNN - 1;
            while (j > 0 && (d < ld[j - 1] || (d == ld[j - 1] && p < li[j - 1]))) {
                ld[j] = ld[j - 1]; li[j] = li[j - 1]; --j;
            }
            ld[j] = d; li[j] = p;
        }
    }
    __shared__ float hv[256];
    __shared__ int   hi2[256];
    __shared__ int   ho[256];
    int ptr = 0;
    for (int r = 0; r < KNN; ++r) {
        hv[tid]  = (ptr < KNN) ? ld[ptr] : 3.4e38f;
        hi2[tid] = (ptr < KNN) ? li[ptr] : 0x7FFFFFFF;
        ho[tid]  = tid;
        __syncthreads();
        for (int s = 128; s > 0; s >>= 1) {
            if (tid < s) {
                const float v2 = hv[tid + s]; const int i2 = hi2[tid + s];
                if (v2 < hv[tid] || (v2 == hv[tid] && i2 < hi2[tid])) {
                    hv[tid] = v2; hi2[tid] = i2; ho[tid] = ho[tid + s];
                }
            }
            __syncthreads();
        }
        if (tid == ho[0]) ptr++;
        if (tid == 0) {
            int ix = hi2[0];
            ix = (ix < 0) ? 0 : ((ix >= PPE) ? (PPE - 1) : ix);
            knn_idx[blk * KNN + r] = base + ix;
        }
        __syncthreads();
    }
}

// ---------------------------------------------------------------------------
// pooled[blk][t] = max over 16 recomputed-pf neighbor rows
// ---------------------------------------------------------------------------
__global__ __launch_bounds__(256) void pool_kernel(const float* __restrict__ pf_nbr,
                                                   float* __restrict__ pooled)
{
    const int blk = blockIdx.x, tid = threadIdx.x;
    for (int t = tid; t < TOKD; t += 256) {
        float mx = -3.4e38f;
#pragma unroll
        for (int j = 0; j < KNN; ++j)
            mx = fmaxf(mx, pf_nbr[(long)(blk * KNN + j) * TOKD + t]);
        pooled[(long)blk * TOKD + t] = mx;
    }
}

// ---------------------------------------------------------------------------
// emit: block b -> event e0+b; stable rank by cent[:,3] asc; fp32 out.
// ---------------------------------------------------------------------------
__global__ __launch_bounds__(256) void emit_kernel(const float* __restrict__ centf,
                                                   const float* __restrict__ tokf,
                                                   int e0, float* __restrict__ out,
                                                   long out_size)
{
    const int e = e0 + blockIdx.x, tid = threadIdx.x;
    const float* tokf_e = tokf + (size_t)blockIdx.x * MT * TOKD;
    __shared__ float tv[MT];
    __shared__ int   rk[MT];
    if (tid < MT) tv[tid] = centf[(long)(e * MT + tid) * 4 + 3];
    __syncthreads();
    if (tid < MT) {
        const float t = tv[tid]; int r = 0;
        for (int j = 0; j < MT; ++j)
            r += (tv[j] < t || (tv[j] == t && j < tid)) ? 1 : 0;
        rk[tid] = r;
    }
    __syncthreads();
    const long cent_off = (long)BATCH * MT * TOKD;
    const long mask_off = cent_off + (long)BATCH * MT * 4;
    for (int idx = tid; idx < MT * TOKD; idx += 256) {
        const int i = idx / TOKD, t = idx % TOKD;
        const long g = ((long)e * MT + rk[i]) * TOKD + t;
        if (g < out_size) out[g] = tokf_e[(long)i * TOKD + t];
    }
    for (int idx = tid; idx < MT * 4; idx += 256) {
        const int i = idx >> 2, d = idx & 3;
        const long g = cent_off + ((long)e * MT + rk[i]) * 4 + d;
        if (g < out_size) out[g] = centf[((long)e * MT + i) * 4 + d];
    }
    for (int idx = tid; idx < MT; idx += 256) {
        const long g = mask_off + (long)e * MT + idx;
        if (g < out_size) out[g] = 1.0f;
    }
}

// ---------------------------------------------------------------------------
extern "C" void kernel_launch(void* const* d_in, const int* in_sizes, int n_in,
                              void* d_out, int out_size, void* d_ws, size_t ws_size,
                              hipStream_t stream)
{
    const float* coords = (const float*)d_in[0];
    const float* feats  = (const float*)d_in[1];
    const float* lt     = (const float*)d_in[2];
    const float* w1  = (const float*)d_in[3];  const float* b1  = (const float*)d_in[4];
    const float* w2  = (const float*)d_in[5];  const float* b2  = (const float*)d_in[6];
    const float* w3  = (const float*)d_in[7];  const float* b3  = (const float*)d_in[8];
    const float* w4  = (const float*)d_in[9];  const float* b4  = (const float*)d_in[10];
    const float* iw1 = (const float*)d_in[11]; const float* ib1 = (const float*)d_in[12];
    const float* lng = (const float*)d_in[13]; const float* lnb = (const float*)d_in[14];
    const float* iw2 = (const float*)d_in[15]; const float* ib2 = (const float*)d_in[16];
    const float* iw3 = (const float*)d_in[17]; const float* ib3 = (const float*)d_in[18];
    const float* nw1 = (const float*)d_in[19]; const float* nb1 = (const float*)d_in[20];
    const float* nw2 = (const float*)d_in[21]; const float* nb2 = (const float*)d_in[22];
    const float* noise = (const float*)d_in[23];

    // ---- ws layout ----
    const size_t FIXED_FL = (size_t)NPT + 4096 + 16384 + (size_t)1024 * TOKD
                          + (size_t)NPT * 4;   // + c4f
    const size_t s_w2 = 512 * 256,  s_w3 = 768 * 512,  s_w4 = 768 * 768;
    const size_t s_i1 = 256 * 800,  s_i2 = 256 * 256;
    const size_t s_n1 = 768 * 768,  s_n2 = 768 * 768;
    const size_t WTOT = 2 * (s_w2 + s_w3 + s_w4 + s_i1 + s_i2 + s_n1 + s_n2);
    const size_t BASE_BYTES = FIXED_FL * 4 + WTOT * 2;
    const size_t PERROW = 10368;
    int ch = 128;
    while (ch < NPT && BASE_BYTES + (size_t)(ch * 2) * PERROW <= ws_size) ch <<= 1;

    float*  pert   = (float*)d_ws;                       // NPT
    float*  centf  = pert + NPT;                         // 1024*4
    int*    knn    = (int*)(centf + 4096);               // 16384 ints
    float*  pooled = (float*)(knn + 16384);              // 1024*768
    float4* c4f    = (float4*)(pooled + (size_t)1024 * TOKD);   // NPT float4
    short*  wsp    = (short*)(c4f + NPT);
    short* w2h = wsp;            short* w2l = w2h + s_w2;
    short* w3h = w2l + s_w2;     short* w3l = w3h + s_w3;
    short* w4h = w3l + s_w3;     short* w4l = w4h + s_w4;
    short* i1h = w4l + s_w4;     short* i1l = i1h + s_i1;
    short* i2h = i1l + s_i1;     short* i2l = i2h + s_i2;
    short* n1h = i2l + s_i2;     short* n1l = n1h + s_n1;
    short* n2h = n1l + s_n1;     short* n2l = n2h + s_n2;
    short* P1h = n2l + s_n2;     short* P1l = P1h + (size_t)ch * 768;
    short* P2h = P1l + (size_t)ch * 768;
    short* P2l = P2h + (size_t)ch * 800;
    float* F1  = (float*)(P2l + (size_t)ch * 800);      // ch*768 fp32
    float* F2  = F1 + (size_t)ch * 768;                 // ch*256 fp32

    // ---- prep + pre-convert weights ----
    prep_kernel<<<dim3((NPT + 255) / 256), dim3(256), 0, stream>>>(coords, c4f);
    wsplit_kernel<<<dim3(512), dim3(256), 0, stream>>>(w2, 256, 512, 256, w2h, w2l);
    wsplit_kernel<<<dim3(768), dim3(256), 0, stream>>>(w3, 512, 768, 512, w3h, w3l);
    wsplit_kernel<<<dim3(768), dim3(256), 0, stream>>>(w4, 768, 768, 768, w4h, w4l);
    wsplit_kernel<<<dim3(256), dim3(256), 0, stream>>>(iw1, 772, 256, 800, i1h, i1l);
    wsplit_kernel<<<dim3(256), dim3(256), 0, stream>>>(iw2, 256, 256, 256, i2h, i2l);
    wsplit_kernel<<<dim3(768), dim3(256), 0, stream>>>(nw1, 768, 768, 768, n1h, n1l);
    wsplit_kernel<<<dim3(768), dim3(256), 0, stream>>>(nw2, 768, 768, 768, n2h, n2l);

    // ---- chunked MLP: features -> pert (selection chain) ----
    for (int ck = 0; ck < NPT / ch; ++ck) {
        const int base = ck * ch;
        l1_kernel<<<dim3(ch), dim3(256), 0, stream>>>(feats, w1, b1, P1h, P1l, base, nullptr);
        gemm_mf<<<dim3(512 / 128, ch / 128), dim3(256), 0, stream>>>(
            P1h, P1l, nullptr, 256, w2h, w2l, b2, P2h, P2l, 512, nullptr, 512, 1);
        gemm_mf<<<dim3(768 / 128, ch / 128), dim3(256), 0, stream>>>(
            P2h, P2l, nullptr, 512, w3h, w3l, b3, P1h, P1l, 768, nullptr, 768, 1);
        gemm_mf<<<dim3(768 / 128, ch / 128), dim3(256), 0, stream>>>(
            P1h, P1l, nullptr, 768, w4h, w4l, b4, P2h, P2l, 800, nullptr, 768, 0);
        a2fill_kernel<<<dim3((ch * 32 + 255) / 256), dim3(256), 0, stream>>>(
            coords, base, ch, P2h, P2l);
        gemm_mf<<<dim3(256 / 128, ch / 128), dim3(256), 0, stream>>>(
            P2h, P2l, nullptr, 800, i1h, i1l, ib1, nullptr, nullptr, 0, F2, 256, 1);
        ln_kernel<<<dim3(ch), dim3(256), 0, stream>>>(F2, lng, lnb, P1h, P1l);
        gemm_mf<<<dim3(256 / 128, ch / 128), dim3(256), 0, stream>>>(
            P1h, P1l, nullptr, 256, i2h, i2l, ib2, nullptr, nullptr, 0, F1, 256, 1);
        imp_kernel<<<dim3(ch), dim3(256), 0, stream>>>(F1, iw3, ib3, noise, lt, pert, base);
    }

    // ---- selection + KNN ----
    topk_kernel<<<dim3(BATCH), dim3(256), 0, stream>>>(pert, c4f, centf);
    knn_kernel<<<dim3(BATCH * MT), dim3(256), 0, stream>>>(c4f, centf, knn);

    // ---- recompute pf for the 16384 gathered neighbor rows (chunked), pool --
    const int NBR  = BATCH * MT * KNN;   // 16384
    const int rcch = (ch < NBR) ? ch : NBR;
    for (int rc = 0; rc < NBR / rcch; ++rc) {
        l1_kernel<<<dim3(rcch), dim3(256), 0, stream>>>(feats, w1, b1, P1h, P1l, 0, knn + (size_t)rc * rcch);
        gemm_mf<<<dim3(512 / 128, rcch / 128), dim3(256), 0, stream>>>(
            P1h, P1l, nullptr, 256, w2h, w2l, b2, P2h, P2l, 512, nullptr, 512, 1);
        gemm_mf<<<dim3(768 / 128, rcch / 128), dim3(256), 0, stream>>>(
            P2h, P2l, nullptr, 512, w3h, w3l, b3, P1h, P1l, 768, nullptr, 768, 1);
        gemm_mf<<<dim3(768 / 128, rcch / 128), dim3(256), 0, stream>>>(
            P1h, P1l, nullptr, 768, w4h, w4l, b4, nullptr, nullptr, 0, F1, 768, 0);
        pool_kernel<<<dim3(rcch / KNN), dim3(256), 0, stream>>>(
            F1, pooled + (size_t)rc * (rcch / KNN) * TOKD);
    }

    // ---- token MLP (1024x768, fp32-A mode) + emit ----
    if (ch >= 1024) {
        float* t1   = (float*)P1h;                 // overlay plane region
        float* tokf = t1 + (size_t)1024 * TOKD;
        gemm_mf<<<dim3(768 / 128, 1024 / 128), dim3(256), 0, stream>>>(
            nullptr, nullptr, pooled, 768, n1h, n1l, nb1, nullptr, nullptr, 0, t1, 768, 1);
        gemm_mf<<<dim3(768 / 128, 1024 / 128), dim3(256), 0, stream>>>(
            nullptr, nullptr, t1, 768, n2h, n2l, nb2, nullptr, nullptr, 0, tokf, 768, 0);
        emit_kernel<<<dim3(BATCH), dim3(256), 0, stream>>>(
            centf, tokf, 0, (float*)d_out, (long)out_size);
    } else {
        float* t1   = (float*)P1h;                 // 128*768 each, fits ch>=128
        float* tokf = t1 + (size_t)MT * TOKD;
        for (int e = 0; e < BATCH; ++e) {
            gemm_mf<<<dim3(768 / 128, 1), dim3(256), 0, stream>>>(
                nullptr, nullptr, pooled + (size_t)e * MT * TOKD, 768,
                n1h, n1l, nb1, nullptr, nullptr, 0, t1, 768, 1);
            gemm_mf<<<dim3(768 / 128, 1), dim3(256), 0, stream>>>(
                nullptr, nullptr, t1, 768, n2h, n2l, nb2, nullptr, nullptr, 0, tokf, 768, 0);
            emit_kernel<<<dim3(1), dim3(256), 0, stream>>>(
                centf, tokf, e, (float*)d_out, (long)out_size);
        }
    }
}